// Round 1
// baseline (2437.620 us; speedup 1.0000x reference)
//
#include <hip/hip_runtime.h>
#include <hip/hip_bf16.h>
#include <math.h>

// Problem constants
#define BB   2
#define CM   192        // D_MODEL
#define DI   384        // D_INNER
#define LL   16384      // D*H*W = 32*32*16
#define NST  16         // D_STATE
#define RDT  12         // DT_RANK
#define XJ   44         // DT_RANK + 2*D_STATE
#define NC   128        // scan chunks
#define CLEN 128        // chunk length (NC*CLEN == LL)

// ---------------------------------------------------------------------------
// Kernel 0: PW = proj_w(192x192) @ out_proj_w(192x384)
__global__ __launch_bounds__(256) void fuse_proj_kernel(
    const float* __restrict__ pw, const float* __restrict__ ow, float* __restrict__ PW) {
  int idx = blockIdx.x * 256 + threadIdx.x;
  if (idx >= CM * DI) return;
  int o = idx / DI, d = idx % DI;
  float s = 0.f;
  #pragma unroll 4
  for (int c = 0; c < CM; c++) s += pw[o * CM + c] * ow[c * DI + d];
  PW[idx] = s;
}

// ---------------------------------------------------------------------------
// Kernel 1: per-(b,c) mean / rstd over L
__global__ __launch_bounds__(256) void norm_stats_kernel(
    const float* __restrict__ x, float* __restrict__ mu, float* __restrict__ rstd) {
  int bc = blockIdx.x;
  const float* p = x + (size_t)bc * LL;
  float s = 0.f, ss = 0.f;
  for (int i = threadIdx.x * 4; i < LL; i += 256 * 4) {
    float4 v = *(const float4*)(p + i);
    s += v.x + v.y + v.z + v.w;
    ss += v.x * v.x + v.y * v.y + v.z * v.z + v.w * v.w;
  }
  for (int o = 32; o > 0; o >>= 1) {
    s += __shfl_down(s, o, 64);
    ss += __shfl_down(ss, o, 64);
  }
  __shared__ float sb[4], ssb[4];
  int wid = threadIdx.x >> 6;
  if ((threadIdx.x & 63) == 0) { sb[wid] = s; ssb[wid] = ss; }
  __syncthreads();
  if (threadIdx.x == 0) {
    s = sb[0] + sb[1] + sb[2] + sb[3];
    ss = ssb[0] + ssb[1] + ssb[2] + ssb[3];
    float m = s * (1.f / LL);
    float var = ss * (1.f / LL) - m * m;
    mu[bc] = m;
    rstd[bc] = 1.f / sqrtf(var + 1e-5f);
  }
}

// ---------------------------------------------------------------------------
// Generic tiled SGEMM: C(b) = A(MxK) @ B(b)(KxN) (+bias per row)
// Optional per-K-row normalization of B: (v - mu[k]) * rstd[k]  (batch-indexed)
__global__ __launch_bounds__(256) void sgemm_kernel(
    const float* __restrict__ A, const float* __restrict__ B, float* __restrict__ C,
    int M, int N, int K, long strideB, long strideC,
    const float* __restrict__ bias,
    const float* __restrict__ mu, const float* __restrict__ rstd, int normStride) {
  __shared__ float As[16][132];
  __shared__ float Bs[16][132];
  int tid = threadIdx.x;
  int bz = blockIdx.z;
  const float* Bp = B + (size_t)bz * strideB;
  float* Cp = C + (size_t)bz * strideC;
  const float* mup = mu ? mu + bz * normStride : nullptr;
  const float* rsp = rstd ? rstd + bz * normStride : nullptr;
  int m0 = blockIdx.y * 128, n0 = blockIdx.x * 128;
  int tx = tid & 15, ty = tid >> 4;

  float acc[8][8];
  #pragma unroll
  for (int i = 0; i < 8; i++)
    #pragma unroll
    for (int j = 0; j < 8; j++) acc[i][j] = 0.f;

  int arow = tid >> 2;          // 0..63
  int acol = (tid & 3) << 2;    // 0,4,8,12
  int brow = tid >> 5;          // 0..7
  int bcol = (tid & 31) << 2;   // 0..124

  for (int k0 = 0; k0 < K; k0 += 16) {
    #pragma unroll
    for (int r = 0; r < 2; r++) {
      int row = arow + r * 64;
      float4 v = make_float4(0.f, 0.f, 0.f, 0.f);
      if (m0 + row < M) v = *(const float4*)(A + (size_t)(m0 + row) * K + k0 + acol);
      As[acol + 0][row] = v.x;
      As[acol + 1][row] = v.y;
      As[acol + 2][row] = v.z;
      As[acol + 3][row] = v.w;
    }
    #pragma unroll
    for (int r = 0; r < 2; r++) {
      int row = brow + r * 8;
      float4 v = *(const float4*)(Bp + (size_t)(k0 + row) * N + n0 + bcol);
      if (mup) {
        float m_ = mup[k0 + row], rs_ = rsp[k0 + row];
        v.x = (v.x - m_) * rs_; v.y = (v.y - m_) * rs_;
        v.z = (v.z - m_) * rs_; v.w = (v.w - m_) * rs_;
      }
      *(float4*)(&Bs[row][bcol]) = v;
    }
    __syncthreads();
    #pragma unroll
    for (int kk = 0; kk < 16; kk++) {
      float a[8], bb[8];
      *(float4*)(&a[0]) = *(const float4*)(&As[kk][ty * 8]);
      *(float4*)(&a[4]) = *(const float4*)(&As[kk][ty * 8 + 4]);
      *(float4*)(&bb[0]) = *(const float4*)(&Bs[kk][tx * 8]);
      *(float4*)(&bb[4]) = *(const float4*)(&Bs[kk][tx * 8 + 4]);
      #pragma unroll
      for (int i = 0; i < 8; i++)
        #pragma unroll
        for (int j = 0; j < 8; j++) acc[i][j] += a[i] * bb[j];
    }
    __syncthreads();
  }
  #pragma unroll
  for (int i = 0; i < 8; i++) {
    int rr = m0 + ty * 8 + i;
    if (rr < M) {
      float bv = bias ? bias[rr] : 0.f;
      float4 v0 = make_float4(acc[i][0] + bv, acc[i][1] + bv, acc[i][2] + bv, acc[i][3] + bv);
      float4 v1 = make_float4(acc[i][4] + bv, acc[i][5] + bv, acc[i][6] + bv, acc[i][7] + bv);
      *(float4*)(Cp + (size_t)rr * N + n0 + tx * 8) = v0;
      *(float4*)(Cp + (size_t)rr * N + n0 + tx * 8 + 4) = v1;
    }
  }
}

// ---------------------------------------------------------------------------
// Kernel 3: causal depthwise conv (k=4) + bias + SiLU.  u_raw = xz rows 0..383
__global__ __launch_bounds__(256) void conv_silu_kernel(
    const float* __restrict__ xz, const float* __restrict__ conv_w,
    const float* __restrict__ conv_b, float* __restrict__ u_conv) {
  int idx = blockIdx.x * 256 + threadIdx.x;  // over BB*DI*LL
  int t = idx & (LL - 1);
  int row = idx >> 14;            // b*DI + d
  int d = row % DI, b = row / DI;
  const float* up = xz + ((size_t)(b * 2 * DI + d)) * LL;
  float w0 = conv_w[d * 4 + 0], w1 = conv_w[d * 4 + 1];
  float w2 = conv_w[d * 4 + 2], w3 = conv_w[d * 4 + 3];
  float acc = conv_b[d] + w3 * up[t];
  if (t >= 1) acc += w2 * up[t - 1];
  if (t >= 2) acc += w1 * up[t - 2];
  if (t >= 3) acc += w0 * up[t - 3];
  float sg = 1.f / (1.f + expf(-acc));
  u_conv[(size_t)row * LL + t] = acc * sg;
}

// ---------------------------------------------------------------------------
// Kernel 5: dt = softplus(dt_proj_w @ dt_low + dt_proj_b), dt_low = dbl rows 0..11
__global__ __launch_bounds__(256) void dt_kernel(
    const float* __restrict__ dbl, const float* __restrict__ dtw,
    const float* __restrict__ dtb, float* __restrict__ dt) {
  int blk = blockIdx.x;           // (b*DI+d)*64 + tch
  int tch = blk & 63;
  int row = blk >> 6;             // b*DI + d
  int d = row % DI, b = row / DI;
  int t = tch * 256 + threadIdx.x;
  float acc = dtb[d];
  const float* dp = dbl + (size_t)b * XJ * LL + t;
  #pragma unroll
  for (int r = 0; r < RDT; r++) acc += dtw[d * RDT + r] * dp[(size_t)r * LL];
  float v = (acc > 20.f) ? acc : log1pf(expf(acc));
  dt[(size_t)row * LL + t] = v;
}

// ---------------------------------------------------------------------------
// Scan phase 1: per (b,d,chunk) compute local end-state h (from 0) and decay product P.
// 16 lanes = 16 states.
__global__ __launch_bounds__(256) void scan_phase1(
    const float* __restrict__ dt, const float* __restrict__ u, const float* __restrict__ dbl,
    const float* __restrict__ A_log, float* __restrict__ hend, float* __restrict__ Pbuf) {
  int tid = threadIdx.x;
  int lane = tid & 15;
  int g = blockIdx.x * 16 + (tid >> 4);
  int chunk = g & (NC - 1);
  int bd = g >> 7;                // NC == 128
  int d = bd % DI, b = bd / DI;
  float Av = -expf(A_log[d * NST + lane]);
  size_t base = (size_t)bd * LL + chunk * CLEN;
  const float* dtp = dt + base;
  const float* up = u + base;
  const float* Bp = dbl + ((size_t)(b * XJ + RDT + lane)) * LL + chunk * CLEN;
  float h = 0.f, P = 1.f;
  for (int i = 0; i < CLEN; i++) {
    float dtv = dtp[i], uv = up[i];
    float dA = __expf(dtv * Av);
    h = dA * h + (dtv * uv) * Bp[i];
    P *= dA;
  }
  size_t o = ((size_t)bd * NC + chunk) * NST + lane;
  hend[o] = h;
  Pbuf[o] = P;
}

// Scan phase 2: serial combine across chunks; overwrites hend with carry-in h0.
__global__ __launch_bounds__(256) void scan_combine(
    float* __restrict__ hend, const float* __restrict__ Pbuf) {
  int idx = blockIdx.x * 256 + threadIdx.x;  // bd*16 + s  (total 12288)
  int lane = idx & 15;
  int bd = idx >> 4;
  float c = 0.f;
  for (int ch = 0; ch < NC; ch++) {
    size_t o = ((size_t)bd * NC + ch) * NST + lane;
    float p = Pbuf[o], he = hend[o];
    hend[o] = c;
    c = p * c + he;
  }
}

// Scan phase 3: replay with carry, produce y = (scan_y + u*D) * silu(z).
// Writes ym into xz rows 0..383 (dead u_raw region).
__global__ __launch_bounds__(256) void scan_phase3(
    const float* __restrict__ dt, const float* __restrict__ u, const float* __restrict__ dbl,
    const float* __restrict__ A_log, const float* __restrict__ hin,
    const float* __restrict__ Dp, float* __restrict__ xz) {
  int tid = threadIdx.x;
  int lane = tid & 15;
  int g = blockIdx.x * 16 + (tid >> 4);
  int chunk = g & (NC - 1);
  int bd = g >> 7;
  int d = bd % DI, b = bd / DI;
  float Av = -expf(A_log[d * NST + lane]);
  size_t base = (size_t)bd * LL + chunk * CLEN;
  const float* dtp = dt + base;
  const float* up = u + base;
  const float* Bp = dbl + ((size_t)(b * XJ + RDT + lane)) * LL + chunk * CLEN;
  const float* Cp = dbl + ((size_t)(b * XJ + RDT + NST + lane)) * LL + chunk * CLEN;
  const float* zp = xz + ((size_t)(b * 2 * DI + DI + d)) * LL + chunk * CLEN;
  float* ymp = xz + ((size_t)(b * 2 * DI + d)) * LL + chunk * CLEN;
  float h = hin[((size_t)bd * NC + chunk) * NST + lane];
  float Dv = Dp[d];
  float ybuf = 0.f;
  for (int i = 0; i < CLEN; i++) {
    float dtv = dtp[i], uv = up[i];
    float dA = __expf(dtv * Av);
    h = dA * h + (dtv * uv) * Bp[i];
    float py = h * Cp[i];
    py += __shfl_xor(py, 8, 16);
    py += __shfl_xor(py, 4, 16);
    py += __shfl_xor(py, 2, 16);
    py += __shfl_xor(py, 1, 16);
    float yv = py + uv * Dv;
    float zv = zp[i];
    yv = yv * (zv / (1.f + expf(-zv)));
    if ((i & 15) == lane) ybuf = yv;
    if ((i & 15) == 15) ymp[(i & ~15) + lane] = ybuf;
  }
}

// ---------------------------------------------------------------------------
extern "C" void kernel_launch(void* const* d_in, const int* in_sizes, int n_in,
                              void* d_out, int out_size, void* d_ws, size_t ws_size,
                              hipStream_t stream) {
  const float* x         = (const float*)d_in[0];
  const float* in_proj_w = (const float*)d_in[1];
  const float* conv_w    = (const float*)d_in[2];
  const float* conv_b    = (const float*)d_in[3];
  const float* x_proj_w  = (const float*)d_in[4];
  const float* dt_proj_w = (const float*)d_in[5];
  const float* dt_proj_b = (const float*)d_in[6];
  const float* A_log     = (const float*)d_in[7];
  const float* D_param   = (const float*)d_in[8];
  const float* out_proj_w= (const float*)d_in[9];
  const float* proj_w    = (const float*)d_in[10];
  const float* proj_b    = (const float*)d_in[11];
  float* out = (float*)d_out;

  // workspace layout (floats)
  float* w = (float*)d_ws;
  float* mu     = w;                     // 384 (pad to 512)
  float* rstd   = w + 512;               // 384 (pad to 512)
  float* PW     = w + 1024;              // 73728
  float* xz     = w + 74752;             // BB*768*LL = 25,165,824
  float* u_conv = xz + (size_t)BB * 2 * DI * LL;        // 12,582,912
  float* dbl    = u_conv + (size_t)BB * DI * LL;        // 1,441,792
  float* dtv    = dbl + (size_t)BB * XJ * LL;           // 12,582,912
  float* hend   = dtv + (size_t)BB * DI * LL;           // 1,572,864
  float* Pbuf   = hend + (size_t)BB * DI * NC * NST;    // 1,572,864
  size_t need = (size_t)(Pbuf - w) + (size_t)BB * DI * NC * NST;
  if (ws_size < need * sizeof(float)) return;  // insufficient workspace -> clean fail

  fuse_proj_kernel<<<dim3((CM * DI + 255) / 256), dim3(256), 0, stream>>>(proj_w, out_proj_w, PW);
  norm_stats_kernel<<<dim3(BB * CM), dim3(256), 0, stream>>>(x, mu, rstd);

  // GEMM1: xz(b,768,L) = in_proj_w(768x192) @ normalized x(b,192,L)
  sgemm_kernel<<<dim3(LL / 128, 6, BB), dim3(256), 0, stream>>>(
      in_proj_w, x, xz, 2 * DI, LL, CM,
      (long)CM * LL, (long)2 * DI * LL, nullptr, mu, rstd, CM);

  conv_silu_kernel<<<dim3(BB * DI * LL / 256), dim3(256), 0, stream>>>(xz, conv_w, conv_b, u_conv);

  // GEMM2: dbl(b,44,L) = x_proj_w(44x384) @ u_conv(b,384,L)
  sgemm_kernel<<<dim3(LL / 128, 1, BB), dim3(256), 0, stream>>>(
      x_proj_w, u_conv, dbl, XJ, LL, DI,
      (long)DI * LL, (long)XJ * LL, nullptr, nullptr, nullptr, 0);

  dt_kernel<<<dim3(BB * DI * 64), dim3(256), 0, stream>>>(dbl, dt_proj_w, dt_proj_b, dtv);

  scan_phase1<<<dim3(BB * DI * NC / 16), dim3(256), 0, stream>>>(dtv, u_conv, dbl, A_log, hend, Pbuf);
  scan_combine<<<dim3(BB * DI * NST / 256), dim3(256), 0, stream>>>(hend, Pbuf);
  scan_phase3<<<dim3(BB * DI * NC / 16), dim3(256), 0, stream>>>(dtv, u_conv, dbl, A_log, hend, D_param, xz);

  // GEMM3: out(b,192,L) = PW(192x384) @ ym(b,384,L) + proj_b
  sgemm_kernel<<<dim3(LL / 128, 2, BB), dim3(256), 0, stream>>>(
      PW, xz, out, CM, LL, DI,
      (long)2 * DI * LL, (long)CM * LL, proj_b, nullptr, nullptr, 0);
}

// Round 2
// 834.069 us; speedup vs baseline: 2.9226x; 2.9226x over previous
//
#include <hip/hip_runtime.h>
#include <hip/hip_bf16.h>
#include <math.h>

// Problem constants
#define BB   2
#define CM   192        // D_MODEL
#define DI   384        // D_INNER
#define LL   16384      // D*H*W = 32*32*16
#define NST  16         // D_STATE
#define RDT  12         // DT_RANK
#define XJ   44         // DT_RANK + 2*D_STATE
#define NC   256        // scan chunks
#define CLEN 64         // chunk length (NC*CLEN == LL)

// ---------------------------------------------------------------------------
// Kernel 0: PW = proj_w(192x192) @ out_proj_w(192x384)
__global__ __launch_bounds__(256) void fuse_proj_kernel(
    const float* __restrict__ pw, const float* __restrict__ ow, float* __restrict__ PW) {
  int idx = blockIdx.x * 256 + threadIdx.x;
  if (idx >= CM * DI) return;
  int o = idx / DI, d = idx % DI;
  float s = 0.f;
  #pragma unroll 4
  for (int c = 0; c < CM; c++) s += pw[o * CM + c] * ow[c * DI + d];
  PW[idx] = s;
}

// ---------------------------------------------------------------------------
// Kernel 1: per-(b,c) mean / rstd over L
__global__ __launch_bounds__(256) void norm_stats_kernel(
    const float* __restrict__ x, float* __restrict__ mu, float* __restrict__ rstd) {
  int bc = blockIdx.x;
  const float* p = x + (size_t)bc * LL;
  float s = 0.f, ss = 0.f;
  for (int i = threadIdx.x * 4; i < LL; i += 256 * 4) {
    float4 v = *(const float4*)(p + i);
    s += v.x + v.y + v.z + v.w;
    ss += v.x * v.x + v.y * v.y + v.z * v.z + v.w * v.w;
  }
  for (int o = 32; o > 0; o >>= 1) {
    s += __shfl_down(s, o, 64);
    ss += __shfl_down(ss, o, 64);
  }
  __shared__ float sb[4], ssb[4];
  int wid = threadIdx.x >> 6;
  if ((threadIdx.x & 63) == 0) { sb[wid] = s; ssb[wid] = ss; }
  __syncthreads();
  if (threadIdx.x == 0) {
    s = sb[0] + sb[1] + sb[2] + sb[3];
    ss = ssb[0] + ssb[1] + ssb[2] + ssb[3];
    float m = s * (1.f / LL);
    float var = ss * (1.f / LL) - m * m;
    mu[bc] = m;
    rstd[bc] = 1.f / sqrtf(var + 1e-5f);
  }
}

// ---------------------------------------------------------------------------
// Generic tiled SGEMM: C(b) = A(MxK) @ B(b)(KxN) (+bias per row)
// Optional per-K-row normalization of B: (v - mu[k]) * rstd[k]  (batch-indexed)
__global__ __launch_bounds__(256) void sgemm_kernel(
    const float* __restrict__ A, const float* __restrict__ B, float* __restrict__ C,
    int M, int N, int K, long strideB, long strideC,
    const float* __restrict__ bias,
    const float* __restrict__ mu, const float* __restrict__ rstd, int normStride) {
  __shared__ float As[16][132];
  __shared__ float Bs[16][132];
  int tid = threadIdx.x;
  int bz = blockIdx.z;
  const float* Bp = B + (size_t)bz * strideB;
  float* Cp = C + (size_t)bz * strideC;
  const float* mup = mu ? mu + bz * normStride : nullptr;
  const float* rsp = rstd ? rstd + bz * normStride : nullptr;
  int m0 = blockIdx.y * 128, n0 = blockIdx.x * 128;
  int tx = tid & 15, ty = tid >> 4;

  float acc[8][8];
  #pragma unroll
  for (int i = 0; i < 8; i++)
    #pragma unroll
    for (int j = 0; j < 8; j++) acc[i][j] = 0.f;

  int arow = tid >> 2;          // 0..63
  int acol = (tid & 3) << 2;    // 0,4,8,12
  int brow = tid >> 5;          // 0..7
  int bcol = (tid & 31) << 2;   // 0..124

  for (int k0 = 0; k0 < K; k0 += 16) {
    #pragma unroll
    for (int r = 0; r < 2; r++) {
      int row = arow + r * 64;
      float4 v = make_float4(0.f, 0.f, 0.f, 0.f);
      if (m0 + row < M) v = *(const float4*)(A + (size_t)(m0 + row) * K + k0 + acol);
      As[acol + 0][row] = v.x;
      As[acol + 1][row] = v.y;
      As[acol + 2][row] = v.z;
      As[acol + 3][row] = v.w;
    }
    #pragma unroll
    for (int r = 0; r < 2; r++) {
      int row = brow + r * 8;
      float4 v = *(const float4*)(Bp + (size_t)(k0 + row) * N + n0 + bcol);
      if (mup) {
        float m_ = mup[k0 + row], rs_ = rsp[k0 + row];
        v.x = (v.x - m_) * rs_; v.y = (v.y - m_) * rs_;
        v.z = (v.z - m_) * rs_; v.w = (v.w - m_) * rs_;
      }
      *(float4*)(&Bs[row][bcol]) = v;
    }
    __syncthreads();
    #pragma unroll
    for (int kk = 0; kk < 16; kk++) {
      float a[8], bb[8];
      *(float4*)(&a[0]) = *(const float4*)(&As[kk][ty * 8]);
      *(float4*)(&a[4]) = *(const float4*)(&As[kk][ty * 8 + 4]);
      *(float4*)(&bb[0]) = *(const float4*)(&Bs[kk][tx * 8]);
      *(float4*)(&bb[4]) = *(const float4*)(&Bs[kk][tx * 8 + 4]);
      #pragma unroll
      for (int i = 0; i < 8; i++)
        #pragma unroll
        for (int j = 0; j < 8; j++) acc[i][j] += a[i] * bb[j];
    }
    __syncthreads();
  }
  #pragma unroll
  for (int i = 0; i < 8; i++) {
    int rr = m0 + ty * 8 + i;
    if (rr < M) {
      float bv = bias ? bias[rr] : 0.f;
      float4 v0 = make_float4(acc[i][0] + bv, acc[i][1] + bv, acc[i][2] + bv, acc[i][3] + bv);
      float4 v1 = make_float4(acc[i][4] + bv, acc[i][5] + bv, acc[i][6] + bv, acc[i][7] + bv);
      *(float4*)(Cp + (size_t)rr * N + n0 + tx * 8) = v0;
      *(float4*)(Cp + (size_t)rr * N + n0 + tx * 8 + 4) = v1;
    }
  }
}

// ---------------------------------------------------------------------------
// Kernel 3: causal depthwise conv (k=4) + bias + SiLU.  u_raw = xz rows 0..383
__global__ __launch_bounds__(256) void conv_silu_kernel(
    const float* __restrict__ xz, const float* __restrict__ conv_w,
    const float* __restrict__ conv_b, float* __restrict__ u_conv) {
  int idx = blockIdx.x * 256 + threadIdx.x;  // over BB*DI*LL
  int t = idx & (LL - 1);
  int row = idx >> 14;            // b*DI + d
  int d = row % DI, b = row / DI;
  const float* up = xz + ((size_t)(b * 2 * DI + d)) * LL;
  float w0 = conv_w[d * 4 + 0], w1 = conv_w[d * 4 + 1];
  float w2 = conv_w[d * 4 + 2], w3 = conv_w[d * 4 + 3];
  float acc = conv_b[d] + w3 * up[t];
  if (t >= 1) acc += w2 * up[t - 1];
  if (t >= 2) acc += w1 * up[t - 2];
  if (t >= 3) acc += w0 * up[t - 3];
  float sg = 1.f / (1.f + expf(-acc));
  u_conv[(size_t)row * LL + t] = acc * sg;
}

// ---------------------------------------------------------------------------
// Kernel 5: dt = softplus(dt_proj_w @ dt_low + dt_proj_b), dt_low = dbl rows 0..11
__global__ __launch_bounds__(256) void dt_kernel(
    const float* __restrict__ dbl, const float* __restrict__ dtw,
    const float* __restrict__ dtb, float* __restrict__ dt) {
  int blk = blockIdx.x;           // (b*DI+d)*64 + tch
  int tch = blk & 63;
  int row = blk >> 6;             // b*DI + d
  int d = row % DI, b = row / DI;
  int t = tch * 256 + threadIdx.x;
  float acc = dtb[d];
  const float* dp = dbl + (size_t)b * XJ * LL + t;
  #pragma unroll
  for (int r = 0; r < RDT; r++) acc += dtw[d * RDT + r] * dp[(size_t)r * LL];
  float v = (acc > 20.f) ? acc : log1pf(expf(acc));
  dt[(size_t)row * LL + t] = v;
}

// ---------------------------------------------------------------------------
// Scan phase 1: one THREAD per (b,d,chunk); all 16 states in registers.
// Block = 128 threads sharing the same (b, chunk) -> B loads are wave-uniform.
__global__ __launch_bounds__(128) void scan_phase1(
    const float* __restrict__ dt, const float* __restrict__ u, const float* __restrict__ dbl,
    const float* __restrict__ A_log, float* __restrict__ hend, float* __restrict__ Pbuf) {
  int chunk = blockIdx.x & (NC - 1);
  int bdg = blockIdx.x / NC;      // 0..5
  int b = bdg / 3;                // block-uniform
  int d = (bdg % 3) * 128 + threadIdx.x;
  int bd = b * DI + d;
  int t0 = chunk * CLEN;

  float av[NST];
  #pragma unroll
  for (int s = 0; s < NST; s++) av[s] = -expf(A_log[d * NST + s]);

  const float* dtp = dt + (size_t)bd * LL + t0;
  const float* up  = u  + (size_t)bd * LL + t0;
  const float* Bb  = dbl + ((size_t)b * XJ + RDT) * LL + t0;   // row s at s*LL

  float h[NST];
  #pragma unroll
  for (int s = 0; s < NST; s++) h[s] = 0.f;
  float S = 0.f;

  for (int t = 0; t < CLEN; t += 4) {
    float4 d4 = *(const float4*)(dtp + t);
    float4 u4 = *(const float4*)(up + t);
    float q0 = d4.x * u4.x, q1 = d4.y * u4.y, q2 = d4.z * u4.z, q3 = d4.w * u4.w;
    S += d4.x + d4.y + d4.z + d4.w;
    #pragma unroll
    for (int s = 0; s < NST; s++) {
      float4 B4 = *(const float4*)(Bb + (size_t)s * LL + t);
      float hh = h[s];
      hh = __expf(d4.x * av[s]) * hh + q0 * B4.x;
      hh = __expf(d4.y * av[s]) * hh + q1 * B4.y;
      hh = __expf(d4.z * av[s]) * hh + q2 * B4.z;
      hh = __expf(d4.w * av[s]) * hh + q3 * B4.w;
      h[s] = hh;
    }
  }
  size_t o = ((size_t)bd * NC + chunk) * NST;
  #pragma unroll
  for (int s = 0; s < NST; s += 4)
    *(float4*)(hend + o + s) = make_float4(h[s], h[s+1], h[s+2], h[s+3]);
  #pragma unroll
  for (int s = 0; s < NST; s += 4)
    *(float4*)(Pbuf + o + s) = make_float4(__expf(S * av[s]), __expf(S * av[s+1]),
                                           __expf(S * av[s+2]), __expf(S * av[s+3]));
}

// Scan phase 2: serial combine across chunks; overwrites hend with carry-in h0.
__global__ __launch_bounds__(256) void scan_combine(
    float* __restrict__ hend, const float* __restrict__ Pbuf) {
  int idx = blockIdx.x * 256 + threadIdx.x;  // bd*16 + s  (total 12288)
  int lane = idx & 15;
  int bd = idx >> 4;
  float c = 0.f;
  for (int ch = 0; ch < NC; ch++) {
    size_t o = ((size_t)bd * NC + ch) * NST + lane;
    float p = Pbuf[o], he = hend[o];
    hend[o] = c;
    c = p * c + he;
  }
}

// Scan phase 3: replay with carry; y = (scan_y + u*D) * silu(z).
// Writes ym into xz rows 0..383 (dead u_raw region). 64B output bursts.
__global__ __launch_bounds__(128) void scan_phase3(
    const float* __restrict__ dt, const float* __restrict__ u, const float* __restrict__ dbl,
    const float* __restrict__ A_log, const float* __restrict__ hin,
    const float* __restrict__ Dp, float* __restrict__ xz) {
  int chunk = blockIdx.x & (NC - 1);
  int bdg = blockIdx.x / NC;
  int b = bdg / 3;                // block-uniform
  int d = (bdg % 3) * 128 + threadIdx.x;
  int bd = b * DI + d;
  int t0 = chunk * CLEN;

  float av[NST];
  #pragma unroll
  for (int s = 0; s < NST; s++) av[s] = -expf(A_log[d * NST + s]);

  const float* dtp = dt + (size_t)bd * LL + t0;
  const float* up  = u  + (size_t)bd * LL + t0;
  const float* Bb  = dbl + ((size_t)b * XJ + RDT) * LL + t0;
  const float* Cb  = dbl + ((size_t)b * XJ + RDT + NST) * LL + t0;
  const float* zp  = xz + ((size_t)(b * 2 * DI + DI + d)) * LL + t0;
  float* ymp = xz + ((size_t)(b * 2 * DI + d)) * LL + t0;

  float h[NST];
  const float* hi = hin + ((size_t)bd * NC + chunk) * NST;
  #pragma unroll
  for (int s = 0; s < NST; s += 4) {
    float4 v = *(const float4*)(hi + s);
    h[s] = v.x; h[s+1] = v.y; h[s+2] = v.z; h[s+3] = v.w;
  }
  float Dv = Dp[d];
  float ob[16];

  for (int t16 = 0; t16 < CLEN; t16 += 16) {
    #pragma unroll
    for (int t4 = 0; t4 < 16; t4 += 4) {
      int t = t16 + t4;
      float4 d4 = *(const float4*)(dtp + t);
      float4 u4 = *(const float4*)(up + t);
      float q0 = d4.x * u4.x, q1 = d4.y * u4.y, q2 = d4.z * u4.z, q3 = d4.w * u4.w;
      float y0 = 0.f, y1 = 0.f, y2 = 0.f, y3 = 0.f;
      #pragma unroll
      for (int s = 0; s < NST; s++) {
        float4 B4 = *(const float4*)(Bb + (size_t)s * LL + t);
        float4 C4 = *(const float4*)(Cb + (size_t)s * LL + t);
        float hh = h[s];
        hh = __expf(d4.x * av[s]) * hh + q0 * B4.x;  y0 += hh * C4.x;
        hh = __expf(d4.y * av[s]) * hh + q1 * B4.y;  y1 += hh * C4.y;
        hh = __expf(d4.z * av[s]) * hh + q2 * B4.z;  y2 += hh * C4.z;
        hh = __expf(d4.w * av[s]) * hh + q3 * B4.w;  y3 += hh * C4.w;
        h[s] = hh;
      }
      float4 z4 = *(const float4*)(zp + t);
      ob[t4 + 0] = (y0 + u4.x * Dv) * (z4.x / (1.f + __expf(-z4.x)));
      ob[t4 + 1] = (y1 + u4.y * Dv) * (z4.y / (1.f + __expf(-z4.y)));
      ob[t4 + 2] = (y2 + u4.z * Dv) * (z4.z / (1.f + __expf(-z4.z)));
      ob[t4 + 3] = (y3 + u4.w * Dv) * (z4.w / (1.f + __expf(-z4.w)));
    }
    #pragma unroll
    for (int k = 0; k < 4; k++)
      *(float4*)(ymp + t16 + k * 4) = make_float4(ob[k*4], ob[k*4+1], ob[k*4+2], ob[k*4+3]);
  }
}

// ---------------------------------------------------------------------------
extern "C" void kernel_launch(void* const* d_in, const int* in_sizes, int n_in,
                              void* d_out, int out_size, void* d_ws, size_t ws_size,
                              hipStream_t stream) {
  const float* x         = (const float*)d_in[0];
  const float* in_proj_w = (const float*)d_in[1];
  const float* conv_w    = (const float*)d_in[2];
  const float* conv_b    = (const float*)d_in[3];
  const float* x_proj_w  = (const float*)d_in[4];
  const float* dt_proj_w = (const float*)d_in[5];
  const float* dt_proj_b = (const float*)d_in[6];
  const float* A_log     = (const float*)d_in[7];
  const float* D_param   = (const float*)d_in[8];
  const float* out_proj_w= (const float*)d_in[9];
  const float* proj_w    = (const float*)d_in[10];
  const float* proj_b    = (const float*)d_in[11];
  float* out = (float*)d_out;

  // workspace layout (floats)
  float* w = (float*)d_ws;
  float* mu     = w;                     // 384 (pad to 512)
  float* rstd   = w + 512;               // 384 (pad to 512)
  float* PW     = w + 1024;              // 73728
  float* xz     = w + 74752;             // BB*768*LL = 25,165,824
  float* u_conv = xz + (size_t)BB * 2 * DI * LL;        // 12,582,912
  float* dbl    = u_conv + (size_t)BB * DI * LL;        // 1,441,792
  float* dtv    = dbl + (size_t)BB * XJ * LL;           // 12,582,912
  float* hend   = dtv + (size_t)BB * DI * LL;           // 3,145,728
  float* Pbuf   = hend + (size_t)BB * DI * NC * NST;    // 3,145,728
  size_t need = (size_t)(Pbuf - w) + (size_t)BB * DI * NC * NST;
  if (ws_size < need * sizeof(float)) return;  // insufficient workspace -> clean fail

  fuse_proj_kernel<<<dim3((CM * DI + 255) / 256), dim3(256), 0, stream>>>(proj_w, out_proj_w, PW);
  norm_stats_kernel<<<dim3(BB * CM), dim3(256), 0, stream>>>(x, mu, rstd);

  // GEMM1: xz(b,768,L) = in_proj_w(768x192) @ normalized x(b,192,L)
  sgemm_kernel<<<dim3(LL / 128, 6, BB), dim3(256), 0, stream>>>(
      in_proj_w, x, xz, 2 * DI, LL, CM,
      (long)CM * LL, (long)2 * DI * LL, nullptr, mu, rstd, CM);

  conv_silu_kernel<<<dim3(BB * DI * LL / 256), dim3(256), 0, stream>>>(xz, conv_w, conv_b, u_conv);

  // GEMM2: dbl(b,44,L) = x_proj_w(44x384) @ u_conv(b,384,L)
  sgemm_kernel<<<dim3(LL / 128, 1, BB), dim3(256), 0, stream>>>(
      x_proj_w, u_conv, dbl, XJ, LL, DI,
      (long)DI * LL, (long)XJ * LL, nullptr, nullptr, nullptr, 0);

  dt_kernel<<<dim3(BB * DI * 64), dim3(256), 0, stream>>>(dbl, dt_proj_w, dt_proj_b, dtv);

  scan_phase1<<<dim3(6 * NC), dim3(128), 0, stream>>>(dtv, u_conv, dbl, A_log, hend, Pbuf);
  scan_combine<<<dim3(BB * DI * NST / 256), dim3(256), 0, stream>>>(hend, Pbuf);
  scan_phase3<<<dim3(6 * NC), dim3(128), 0, stream>>>(dtv, u_conv, dbl, A_log, hend, D_param, xz);

  // GEMM3: out(b,192,L) = PW(192x384) @ ym(b,384,L) + proj_b
  sgemm_kernel<<<dim3(LL / 128, 2, BB), dim3(256), 0, stream>>>(
      PW, xz, out, CM, LL, DI,
      (long)2 * DI * LL, (long)CM * LL, proj_b, nullptr, nullptr, 0);
}

// Round 3
// 604.579 us; speedup vs baseline: 4.0319x; 1.3796x over previous
//
#include <hip/hip_runtime.h>
#include <hip/hip_bf16.h>
#include <math.h>

// Problem constants
#define BB   2
#define CM   192        // D_MODEL
#define DI   384        // D_INNER
#define LL   16384      // D*H*W
#define NST  16         // D_STATE
#define RDT  12         // DT_RANK
#define XJ   44         // DT_RANK + 2*D_STATE
#define NC   256        // scan chunks
#define CLEN 64         // chunk length (NC*CLEN == LL)

// ---------------------------------------------------------------------------
// Kernel 0: PW = proj_w(192x192) @ out_proj_w(192x384)
__global__ __launch_bounds__(256) void fuse_proj_kernel(
    const float* __restrict__ pw, const float* __restrict__ ow, float* __restrict__ PW) {
  int idx = blockIdx.x * 256 + threadIdx.x;
  if (idx >= CM * DI) return;
  int o = idx / DI, d = idx % DI;
  float s = 0.f;
  #pragma unroll 4
  for (int c = 0; c < CM; c++) s += pw[o * CM + c] * ow[c * DI + d];
  PW[idx] = s;
}

// ---------------------------------------------------------------------------
// Kernel 1: per-(b,c) mean / rstd over L
__global__ __launch_bounds__(256) void norm_stats_kernel(
    const float* __restrict__ x, float* __restrict__ mu, float* __restrict__ rstd) {
  int bc = blockIdx.x;
  const float* p = x + (size_t)bc * LL;
  float s = 0.f, ss = 0.f;
  for (int i = threadIdx.x * 4; i < LL; i += 256 * 4) {
    float4 v = *(const float4*)(p + i);
    s += v.x + v.y + v.z + v.w;
    ss += v.x * v.x + v.y * v.y + v.z * v.z + v.w * v.w;
  }
  for (int o = 32; o > 0; o >>= 1) {
    s += __shfl_down(s, o, 64);
    ss += __shfl_down(ss, o, 64);
  }
  __shared__ float sb[4], ssb[4];
  int wid = threadIdx.x >> 6;
  if ((threadIdx.x & 63) == 0) { sb[wid] = s; ssb[wid] = ss; }
  __syncthreads();
  if (threadIdx.x == 0) {
    s = sb[0] + sb[1] + sb[2] + sb[3];
    ss = ssb[0] + ssb[1] + ssb[2] + ssb[3];
    float m = s * (1.f / LL);
    float var = ss * (1.f / LL) - m * m;
    mu[bc] = m;
    rstd[bc] = 1.f / sqrtf(var + 1e-5f);
  }
}

// ---------------------------------------------------------------------------
// Generic tiled SGEMM: C(b) = A(MxK) @ B(b)(KxN) (+bias per row)
// Optional per-K-row normalization of B: (v - mu[k]) * rstd[k]
__global__ __launch_bounds__(256) void sgemm_kernel(
    const float* __restrict__ A, const float* __restrict__ B, float* __restrict__ C,
    int M, int N, int K, long strideB, long strideC,
    const float* __restrict__ bias,
    const float* __restrict__ mu, const float* __restrict__ rstd, int normStride) {
  __shared__ float As[16][132];
  __shared__ float Bs[16][132];
  int tid = threadIdx.x;
  int bz = blockIdx.z;
  const float* Bp = B + (size_t)bz * strideB;
  float* Cp = C + (size_t)bz * strideC;
  const float* mup = mu ? mu + bz * normStride : nullptr;
  const float* rsp = rstd ? rstd + bz * normStride : nullptr;
  int m0 = blockIdx.y * 128, n0 = blockIdx.x * 128;
  int tx = tid & 15, ty = tid >> 4;

  float acc[8][8];
  #pragma unroll
  for (int i = 0; i < 8; i++)
    #pragma unroll
    for (int j = 0; j < 8; j++) acc[i][j] = 0.f;

  int arow = tid >> 2;
  int acol = (tid & 3) << 2;
  int brow = tid >> 5;
  int bcol = (tid & 31) << 2;

  for (int k0 = 0; k0 < K; k0 += 16) {
    #pragma unroll
    for (int r = 0; r < 2; r++) {
      int row = arow + r * 64;
      float4 v = make_float4(0.f, 0.f, 0.f, 0.f);
      if (m0 + row < M) v = *(const float4*)(A + (size_t)(m0 + row) * K + k0 + acol);
      As[acol + 0][row] = v.x;
      As[acol + 1][row] = v.y;
      As[acol + 2][row] = v.z;
      As[acol + 3][row] = v.w;
    }
    #pragma unroll
    for (int r = 0; r < 2; r++) {
      int row = brow + r * 8;
      float4 v = *(const float4*)(Bp + (size_t)(k0 + row) * N + n0 + bcol);
      if (mup) {
        float m_ = mup[k0 + row], rs_ = rsp[k0 + row];
        v.x = (v.x - m_) * rs_; v.y = (v.y - m_) * rs_;
        v.z = (v.z - m_) * rs_; v.w = (v.w - m_) * rs_;
      }
      *(float4*)(&Bs[row][bcol]) = v;
    }
    __syncthreads();
    #pragma unroll
    for (int kk = 0; kk < 16; kk++) {
      float a[8], bb[8];
      *(float4*)(&a[0]) = *(const float4*)(&As[kk][ty * 8]);
      *(float4*)(&a[4]) = *(const float4*)(&As[kk][ty * 8 + 4]);
      *(float4*)(&bb[0]) = *(const float4*)(&Bs[kk][tx * 8]);
      *(float4*)(&bb[4]) = *(const float4*)(&Bs[kk][tx * 8 + 4]);
      #pragma unroll
      for (int i = 0; i < 8; i++)
        #pragma unroll
        for (int j = 0; j < 8; j++) acc[i][j] += a[i] * bb[j];
    }
    __syncthreads();
  }
  #pragma unroll
  for (int i = 0; i < 8; i++) {
    int rr = m0 + ty * 8 + i;
    if (rr < M) {
      float bv = bias ? bias[rr] : 0.f;
      float4 v0 = make_float4(acc[i][0] + bv, acc[i][1] + bv, acc[i][2] + bv, acc[i][3] + bv);
      float4 v1 = make_float4(acc[i][4] + bv, acc[i][5] + bv, acc[i][6] + bv, acc[i][7] + bv);
      *(float4*)(Cp + (size_t)rr * N + n0 + tx * 8) = v0;
      *(float4*)(Cp + (size_t)rr * N + n0 + tx * 8 + 4) = v1;
    }
  }
}

// ---------------------------------------------------------------------------
// Conv: causal depthwise k=4 + bias + SiLU. Reads xz u-half [d][t].
// Writes u_t [b][t][d] (coalesced, for scan) AND u_scr [b][d][t] (for GEMM2).
__global__ __launch_bounds__(128) void conv_silu_kernel(
    const float* __restrict__ xz, const float* __restrict__ conv_w,
    const float* __restrict__ conv_b, float* __restrict__ u_t, float* __restrict__ u_scr) {
  int tc = blockIdx.x;            // 0..127 (t-chunk of 128)
  int grp = blockIdx.y;           // 0..5
  int b = grp / 3, d0 = (grp % 3) * 128;
  int d = d0 + threadIdx.x;
  int t0 = tc * 128;
  const float* up = xz + ((size_t)(b * 2 * DI + d)) * LL;
  float w0 = conv_w[d * 4 + 0], w1 = conv_w[d * 4 + 1];
  float w2 = conv_w[d * 4 + 2], w3 = conv_w[d * 4 + 3];
  float cb = conv_b[d];
  float xm3 = (t0 >= 3) ? up[t0 - 3] : 0.f;
  float xm2 = (t0 >= 2) ? up[t0 - 2] : 0.f;
  float xm1 = (t0 >= 1) ? up[t0 - 1] : 0.f;
  float* utb = u_t + (size_t)b * LL * DI + (size_t)t0 * DI + d;
  float* usb = u_scr + ((size_t)(b * DI + d)) * LL + t0;
  float ob[4];
  for (int t = 0; t < 128; t += 4) {
    #pragma unroll
    for (int k = 0; k < 4; k++) {
      float xc = up[t0 + t + k];
      float acc = cb + w3 * xc + w2 * xm1 + w1 * xm2 + w0 * xm3;
      float sv = acc / (1.f + expf(-acc));
      utb[(size_t)(t + k) * DI] = sv;
      ob[k] = sv;
      xm3 = xm2; xm2 = xm1; xm1 = xc;
    }
    *(float4*)(usb + t) = make_float4(ob[0], ob[1], ob[2], ob[3]);
  }
}

// ---------------------------------------------------------------------------
// dt kernel: dt_t[b][t][d] = softplus(dt_proj_w @ dbl[0..11] + dt_proj_b)
__global__ __launch_bounds__(128) void dt_kernel(
    const float* __restrict__ dbl, const float* __restrict__ dtw,
    const float* __restrict__ dtb, float* __restrict__ dt_t) {
  __shared__ float Ds[12 * 128];
  int tc = blockIdx.x;            // 0..127
  int grp = blockIdx.y;           // 0..5
  int b = grp / 3, d0 = (grp % 3) * 128;
  int t0 = tc * 128;
  int tid = threadIdx.x;
  const float* dp = dbl + (size_t)b * XJ * LL + t0 + tid;
  #pragma unroll
  for (int r = 0; r < 12; r++) Ds[r * 128 + tid] = dp[(size_t)r * LL];
  int d = d0 + tid;
  float dw[12];
  *(float4*)(dw)     = *(const float4*)(dtw + d * 12);
  *(float4*)(dw + 4) = *(const float4*)(dtw + d * 12 + 4);
  *(float4*)(dw + 8) = *(const float4*)(dtw + d * 12 + 8);
  float db = dtb[d];
  __syncthreads();
  float* outp = dt_t + (size_t)b * LL * DI + (size_t)t0 * DI + d;
  for (int t = 0; t < 128; t++) {
    float acc = db;
    #pragma unroll
    for (int r = 0; r < 12; r++) acc = fmaf(Ds[r * 128 + t], dw[r], acc);
    float v = (acc > 20.f) ? acc : log1pf(expf(acc));
    outp[(size_t)t * DI] = v;
  }
}

// ---------------------------------------------------------------------------
// Scan phase 1: block = (b, chunk), 768 threads: pair (d = tid>>1, half = tid&1),
// 8 states per thread. B staged in LDS. exp-chain fast path (A_log ratios
// integer) with generic fallback.
__global__ __launch_bounds__(768) void scan_phase1(
    const float* __restrict__ dt_t, const float* __restrict__ u_t,
    const float* __restrict__ dbl, const float* __restrict__ A_log,
    float* __restrict__ hend, float* __restrict__ Pbuf) {
  __shared__ __align__(16) float Bs[CLEN * 20];
  int tid = threadIdx.x;
  int chunk = blockIdx.x, b = blockIdx.y;
  int t0 = chunk * CLEN;
  const float* dblB = dbl + ((size_t)b * XJ + RDT) * LL + t0;
  if (tid < 256) {
    int s = tid >> 4, t4 = (tid & 15) << 2;
    float4 v = *(const float4*)(dblB + (size_t)s * LL + t4);
    Bs[(t4 + 0) * 20 + s] = v.x;
    Bs[(t4 + 1) * 20 + s] = v.y;
    Bs[(t4 + 2) * 20 + s] = v.z;
    Bs[(t4 + 3) * 20 + s] = v.w;
  }
  int d = tid >> 1, half = tid & 1, s0 = half * 8;
  int bd = b * DI + d;
  float av0 = -expf(A_log[d * NST]);
  float av_[8];
  bool ok = true;
  #pragma unroll
  for (int j = 0; j < 8; j++) {
    av_[j] = -expf(A_log[d * NST + s0 + j]);
    ok = ok && (fabsf(av_[j] - av0 * (float)(s0 + j + 1)) <= 1e-4f * fabsf(av_[j]));
  }
  __syncthreads();
  const float* dtp = dt_t + (size_t)b * LL * DI + (size_t)t0 * DI + d;
  const float* up  = u_t  + (size_t)b * LL * DI + (size_t)t0 * DI + d;
  float h[8];
  #pragma unroll
  for (int j = 0; j < 8; j++) h[j] = 0.f;
  float S = 0.f;

  if (__all(ok)) {
    for (int t = 0; t < CLEN; t++) {
      float dtv = dtp[(size_t)t * DI];
      float uv  = up[(size_t)t * DI];
      float q = dtv * uv;
      S += dtv;
      float w  = __expf(dtv * av0);
      float dA = __expf(dtv * av_[0]);
      float4 B0 = *(const float4*)(&Bs[t * 20 + s0]);
      float4 B1 = *(const float4*)(&Bs[t * 20 + s0 + 4]);
      h[0] = dA * h[0] + q * B0.x; dA *= w;
      h[1] = dA * h[1] + q * B0.y; dA *= w;
      h[2] = dA * h[2] + q * B0.z; dA *= w;
      h[3] = dA * h[3] + q * B0.w; dA *= w;
      h[4] = dA * h[4] + q * B1.x; dA *= w;
      h[5] = dA * h[5] + q * B1.y; dA *= w;
      h[6] = dA * h[6] + q * B1.z; dA *= w;
      h[7] = dA * h[7] + q * B1.w;
    }
    size_t o = ((size_t)bd * NC + chunk) * NST + s0;
    *(float4*)(hend + o)     = make_float4(h[0], h[1], h[2], h[3]);
    *(float4*)(hend + o + 4) = make_float4(h[4], h[5], h[6], h[7]);
    float p1 = __expf(S * av0);
    float pj = __expf(S * av_[0]);
    float P[8];
    #pragma unroll
    for (int j = 0; j < 8; j++) { P[j] = pj; pj *= p1; }
    *(float4*)(Pbuf + o)     = make_float4(P[0], P[1], P[2], P[3]);
    *(float4*)(Pbuf + o + 4) = make_float4(P[4], P[5], P[6], P[7]);
  } else {
    for (int t = 0; t < CLEN; t++) {
      float dtv = dtp[(size_t)t * DI];
      float uv  = up[(size_t)t * DI];
      float q = dtv * uv;
      S += dtv;
      #pragma unroll
      for (int j = 0; j < 8; j++)
        h[j] = __expf(dtv * av_[j]) * h[j] + q * Bs[t * 20 + s0 + j];
    }
    size_t o = ((size_t)bd * NC + chunk) * NST + s0;
    #pragma unroll
    for (int j = 0; j < 8; j++) {
      hend[o + j] = h[j];
      Pbuf[o + j] = __expf(S * av_[j]);
    }
  }
}

// Scan phase 2: serial combine across chunks; overwrites hend with carry-in h0.
__global__ __launch_bounds__(256) void scan_combine(
    float* __restrict__ hend, const float* __restrict__ Pbuf) {
  int idx = blockIdx.x * 256 + threadIdx.x;  // bd*16 + s
  int lane = idx & 15;
  int bd = idx >> 4;
  float c = 0.f;
  for (int ch = 0; ch < NC; ch++) {
    size_t o = ((size_t)bd * NC + ch) * NST + lane;
    float p = Pbuf[o], he = hend[o];
    hend[o] = c;
    c = p * c + he;
  }
}

// Scan phase 3: replay with carry; y = (scan_y + u*D) * silu(z).
// ym written into xz u-half [d][t].
__global__ __launch_bounds__(768) void scan_phase3(
    const float* __restrict__ dt_t, const float* __restrict__ u_t,
    const float* __restrict__ dbl, const float* __restrict__ A_log,
    const float* __restrict__ hin, const float* __restrict__ Dp,
    float* __restrict__ xz) {
  __shared__ __align__(16) float Bs[CLEN * 20];
  __shared__ __align__(16) float Cs[CLEN * 20];
  int tid = threadIdx.x;
  int chunk = blockIdx.x, b = blockIdx.y;
  int t0 = chunk * CLEN;
  const float* dblB = dbl + ((size_t)b * XJ + RDT) * LL + t0;
  if (tid < 256) {
    int s = tid >> 4, t4 = (tid & 15) << 2;
    float4 v = *(const float4*)(dblB + (size_t)s * LL + t4);
    Bs[(t4 + 0) * 20 + s] = v.x;
    Bs[(t4 + 1) * 20 + s] = v.y;
    Bs[(t4 + 2) * 20 + s] = v.z;
    Bs[(t4 + 3) * 20 + s] = v.w;
  } else if (tid < 512) {
    int q = tid - 256;
    int s = q >> 4, t4 = (q & 15) << 2;
    float4 v = *(const float4*)(dblB + (size_t)(NST + s) * LL + t4);
    Cs[(t4 + 0) * 20 + s] = v.x;
    Cs[(t4 + 1) * 20 + s] = v.y;
    Cs[(t4 + 2) * 20 + s] = v.z;
    Cs[(t4 + 3) * 20 + s] = v.w;
  }
  int d = tid >> 1, half = tid & 1, s0 = half * 8;
  int bd = b * DI + d;
  float av0 = -expf(A_log[d * NST]);
  float av_[8];
  bool ok = true;
  #pragma unroll
  for (int j = 0; j < 8; j++) {
    av_[j] = -expf(A_log[d * NST + s0 + j]);
    ok = ok && (fabsf(av_[j] - av0 * (float)(s0 + j + 1)) <= 1e-4f * fabsf(av_[j]));
  }
  __syncthreads();
  const float* dtp = dt_t + (size_t)b * LL * DI + (size_t)t0 * DI + d;
  const float* up  = u_t  + (size_t)b * LL * DI + (size_t)t0 * DI + d;
  const float* zp  = xz + ((size_t)(b * 2 * DI + DI + d)) * LL + t0;
  float* ymp = xz + ((size_t)(b * 2 * DI + d)) * LL + t0;

  float h[8];
  const float* hi = hin + ((size_t)bd * NC + chunk) * NST + s0;
  float4 h0 = *(const float4*)(hi);
  float4 h1 = *(const float4*)(hi + 4);
  h[0] = h0.x; h[1] = h0.y; h[2] = h0.z; h[3] = h0.w;
  h[4] = h1.x; h[5] = h1.y; h[6] = h1.z; h[7] = h1.w;
  float Dv = Dp[d];
  float ob[4];

  if (__all(ok)) {
    for (int t = 0; t < CLEN; t += 4) {
      #pragma unroll
      for (int k = 0; k < 4; k++) {
        int tt = t + k;
        float dtv = dtp[(size_t)tt * DI];
        float uv  = up[(size_t)tt * DI];
        float q = dtv * uv;
        float w  = __expf(dtv * av0);
        float dA = __expf(dtv * av_[0]);
        float4 B0 = *(const float4*)(&Bs[tt * 20 + s0]);
        float4 B1 = *(const float4*)(&Bs[tt * 20 + s0 + 4]);
        float4 C0 = *(const float4*)(&Cs[tt * 20 + s0]);
        float4 C1 = *(const float4*)(&Cs[tt * 20 + s0 + 4]);
        float y;
        h[0] = dA * h[0] + q * B0.x; y  = h[0] * C0.x; dA *= w;
        h[1] = dA * h[1] + q * B0.y; y += h[1] * C0.y; dA *= w;
        h[2] = dA * h[2] + q * B0.z; y += h[2] * C0.z; dA *= w;
        h[3] = dA * h[3] + q * B0.w; y += h[3] * C0.w; dA *= w;
        h[4] = dA * h[4] + q * B1.x; y += h[4] * C1.x; dA *= w;
        h[5] = dA * h[5] + q * B1.y; y += h[5] * C1.y; dA *= w;
        h[6] = dA * h[6] + q * B1.z; y += h[6] * C1.z; dA *= w;
        h[7] = dA * h[7] + q * B1.w; y += h[7] * C1.w;
        y += __shfl_xor(y, 1);
        float zv = zp[tt];
        float yv = (y + uv * Dv) * (zv / (1.f + __expf(-zv)));
        ob[k] = yv;
      }
      if (half == 0)
        *(float4*)(ymp + t) = make_float4(ob[0], ob[1], ob[2], ob[3]);
    }
  } else {
    for (int t = 0; t < CLEN; t += 4) {
      #pragma unroll
      for (int k = 0; k < 4; k++) {
        int tt = t + k;
        float dtv = dtp[(size_t)tt * DI];
        float uv  = up[(size_t)tt * DI];
        float q = dtv * uv;
        float y = 0.f;
        #pragma unroll
        for (int j = 0; j < 8; j++) {
          h[j] = __expf(dtv * av_[j]) * h[j] + q * Bs[tt * 20 + s0 + j];
          y += h[j] * Cs[tt * 20 + s0 + j];
        }
        y += __shfl_xor(y, 1);
        float zv = zp[tt];
        float yv = (y + uv * Dv) * (zv / (1.f + __expf(-zv)));
        ob[k] = yv;
      }
      if (half == 0)
        *(float4*)(ymp + t) = make_float4(ob[0], ob[1], ob[2], ob[3]);
    }
  }
}

// ---------------------------------------------------------------------------
extern "C" void kernel_launch(void* const* d_in, const int* in_sizes, int n_in,
                              void* d_out, int out_size, void* d_ws, size_t ws_size,
                              hipStream_t stream) {
  const float* x         = (const float*)d_in[0];
  const float* in_proj_w = (const float*)d_in[1];
  const float* conv_w    = (const float*)d_in[2];
  const float* conv_b    = (const float*)d_in[3];
  const float* x_proj_w  = (const float*)d_in[4];
  const float* dt_proj_w = (const float*)d_in[5];
  const float* dt_proj_b = (const float*)d_in[6];
  const float* A_log     = (const float*)d_in[7];
  const float* D_param   = (const float*)d_in[8];
  const float* out_proj_w= (const float*)d_in[9];
  const float* proj_w    = (const float*)d_in[10];
  const float* proj_b    = (const float*)d_in[11];
  float* out = (float*)d_out;

  // workspace layout (floats) — identical footprint to R2 (232.6 MB)
  float* w = (float*)d_ws;
  float* mu     = w;                                    // 512
  float* rstd   = w + 512;                              // 512
  float* PW     = w + 1024;                             // 73728
  float* xz     = w + 74752;                            // 25,165,824
  float* u_t    = xz + (size_t)BB * 2 * DI * LL;        // 12,582,912  [b][t][d]
  float* u_scr  = u_t + (size_t)BB * DI * LL;           // 12,582,912  [b][d][t] -> later dt_t [b][t][d]
  float* dbl    = u_scr + (size_t)BB * DI * LL;         // 1,441,792
  float* hend   = dbl + (size_t)BB * XJ * LL;           // 3,145,728
  float* Pbuf   = hend + (size_t)BB * DI * NC * NST;    // 3,145,728
  size_t need = (size_t)(Pbuf - w) + (size_t)BB * DI * NC * NST;
  if (ws_size < need * sizeof(float)) return;
  float* dt_t = u_scr;   // reuse after GEMM2 consumes u_scr

  fuse_proj_kernel<<<dim3((CM * DI + 255) / 256), dim3(256), 0, stream>>>(proj_w, out_proj_w, PW);
  norm_stats_kernel<<<dim3(BB * CM), dim3(256), 0, stream>>>(x, mu, rstd);

  // GEMM1: xz(b,768,L) = in_proj_w(768x192) @ normalized x(b,192,L)
  sgemm_kernel<<<dim3(LL / 128, 6, BB), dim3(256), 0, stream>>>(
      in_proj_w, x, xz, 2 * DI, LL, CM,
      (long)CM * LL, (long)2 * DI * LL, nullptr, mu, rstd, CM);

  conv_silu_kernel<<<dim3(LL / 128, 6), dim3(128), 0, stream>>>(xz, conv_w, conv_b, u_t, u_scr);

  // GEMM2: dbl(b,44,L) = x_proj_w(44x384) @ u_scr(b,384,L)
  sgemm_kernel<<<dim3(LL / 128, 1, BB), dim3(256), 0, stream>>>(
      x_proj_w, u_scr, dbl, XJ, LL, DI,
      (long)DI * LL, (long)XJ * LL, nullptr, nullptr, nullptr, 0);

  dt_kernel<<<dim3(LL / 128, 6), dim3(128), 0, stream>>>(dbl, dt_proj_w, dt_proj_b, dt_t);

  scan_phase1<<<dim3(NC, BB), dim3(768), 0, stream>>>(dt_t, u_t, dbl, A_log, hend, Pbuf);
  scan_combine<<<dim3(BB * DI * NST / 256), dim3(256), 0, stream>>>(hend, Pbuf);
  scan_phase3<<<dim3(NC, BB), dim3(768), 0, stream>>>(dt_t, u_t, dbl, A_log, hend, D_param, xz);

  // GEMM3: out(b,192,L) = PW(192x384) @ ym(b,384,L) + proj_b
  sgemm_kernel<<<dim3(LL / 128, 2, BB), dim3(256), 0, stream>>>(
      PW, xz, out, CM, LL, DI,
      (long)2 * DI * LL, (long)CM * LL, proj_b, nullptr, nullptr, 0);
}

// Round 4
// 346.123 us; speedup vs baseline: 7.0426x; 1.7467x over previous
//
#include <hip/hip_runtime.h>
#include <hip/hip_bf16.h>
#include <math.h>

// Problem constants
#define BB   2
#define CM   192        // D_MODEL
#define DI   384        // D_INNER
#define LL   16384      // D*H*W
#define NST  16         // D_STATE
#define RDT  12         // DT_RANK
#define XJ   44         // DT_RANK + 2*D_STATE
#define NC   256        // scan chunks
#define CLEN 64         // chunk length
#define DBS  64         // dblT row stride (GEMM2 padded M)
#define XZS  768        // xzT row stride

typedef __attribute__((ext_vector_type(8))) short bf16x8;
typedef __attribute__((ext_vector_type(4))) float f32x4;
typedef unsigned short ushort_t;

static __device__ __forceinline__ ushort_t f2bf(float f) {
  __hip_bfloat16 h = __float2bfloat16(f);
  return *reinterpret_cast<ushort_t*>(&h);
}
static __device__ __forceinline__ float bf2f(ushort_t u) {
  __hip_bfloat16 h;
  *reinterpret_cast<ushort_t*>(&h) = u;
  return __bfloat162float(h);
}

// ---------------------------------------------------------------------------
// PW = proj_w(192x192) @ out_proj_w(192x384)   (fp32, tiny)
__global__ __launch_bounds__(256) void fuse_proj_kernel(
    const float* __restrict__ pw, const float* __restrict__ ow, float* __restrict__ PW) {
  int idx = blockIdx.x * 256 + threadIdx.x;
  if (idx >= CM * DI) return;
  int o = idx / DI, d = idx % DI;
  float s = 0.f;
  #pragma unroll 4
  for (int c = 0; c < CM; c++) s += pw[o * CM + c] * ow[c * DI + d];
  PW[idx] = s;
}

// ---------------------------------------------------------------------------
// Weight conversions to bf16 (x_proj padded 44 -> 64 rows with zeros)
__global__ __launch_bounds__(256) void cvt_weights_kernel(
    const float* __restrict__ ipw, const float* __restrict__ xpw,
    const float* __restrict__ PW,
    ushort_t* __restrict__ ipw_bf, ushort_t* __restrict__ xpw_bf,
    ushort_t* __restrict__ PW_bf) {
  int i = blockIdx.x * 256 + threadIdx.x;
  if (i < 2 * DI * CM) ipw_bf[i] = f2bf(ipw[i]);          // 768x192
  if (i < DBS * DI) {                                      // 64x384 (pad)
    int r = i / DI;
    xpw_bf[i] = (r < XJ) ? f2bf(xpw[i]) : (ushort_t)0;
  }
  if (i < CM * DI) PW_bf[i] = f2bf(PW[i]);                 // 192x384
}

// ---------------------------------------------------------------------------
// per-(b,c) mean / rstd over L
__global__ __launch_bounds__(256) void norm_stats_kernel(
    const float* __restrict__ x, float* __restrict__ mu, float* __restrict__ rstd) {
  int bc = blockIdx.x;
  const float* p = x + (size_t)bc * LL;
  float s = 0.f, ss = 0.f;
  for (int i = threadIdx.x * 4; i < LL; i += 256 * 4) {
    float4 v = *(const float4*)(p + i);
    s += v.x + v.y + v.z + v.w;
    ss += v.x * v.x + v.y * v.y + v.z * v.z + v.w * v.w;
  }
  for (int o = 32; o > 0; o >>= 1) {
    s += __shfl_down(s, o, 64);
    ss += __shfl_down(ss, o, 64);
  }
  __shared__ float sb[4], ssb[4];
  int wid = threadIdx.x >> 6;
  if ((threadIdx.x & 63) == 0) { sb[wid] = s; ssb[wid] = ss; }
  __syncthreads();
  if (threadIdx.x == 0) {
    s = sb[0] + sb[1] + sb[2] + sb[3];
    ss = ssb[0] + ssb[1] + ssb[2] + ssb[3];
    float m = s * (1.f / LL);
    float var = ss * (1.f / LL) - m * m;
    mu[bc] = m;
    rstd[bc] = 1.f / sqrtf(var + 1e-5f);
  }
}

// ---------------------------------------------------------------------------
// xT[b][t][c] bf16 = normalized x (LDS 64x64 transpose tile)
__global__ __launch_bounds__(256) void xt_norm_kernel(
    const float* __restrict__ x, const float* __restrict__ mu,
    const float* __restrict__ rstd, ushort_t* __restrict__ xT) {
  __shared__ ushort_t T[64][72];
  int t0 = blockIdx.x * 64, c0 = blockIdx.y * 64, b = blockIdx.z;
  int tid = threadIdx.x;
  int c = tid >> 2, tq = (tid & 3) * 16;
  int bc = b * CM + c0 + c;
  const float* xp = x + (size_t)bc * LL + t0 + tq;
  float m = mu[bc], rs = rstd[bc];
  #pragma unroll
  for (int j = 0; j < 16; j += 4) {
    float4 v = *(const float4*)(xp + j);
    T[c][tq + j + 0] = f2bf((v.x - m) * rs);
    T[c][tq + j + 1] = f2bf((v.y - m) * rs);
    T[c][tq + j + 2] = f2bf((v.z - m) * rs);
    T[c][tq + j + 3] = f2bf((v.w - m) * rs);
  }
  __syncthreads();
  int t = tid >> 2, cq = (tid & 3) * 16;
  unsigned int ob[8];
  #pragma unroll
  for (int j = 0; j < 8; j++)
    ob[j] = (unsigned int)T[cq + 2 * j][t] | ((unsigned int)T[cq + 2 * j + 1][t] << 16);
  ushort_t* op = xT + ((size_t)b * LL + t0 + t) * CM + c0 + cq;
  *(uint4*)(op)     = make_uint4(ob[0], ob[1], ob[2], ob[3]);
  *(uint4*)(op + 8) = make_uint4(ob[4], ob[5], ob[6], ob[7]);
}

// ---------------------------------------------------------------------------
// MFMA bf16 GEMM.  A[Mp][K] bf16 row-major (weights, Mp mult of 64).
// BT[b][N][K] bf16 row-major (activations, time-major).
// TOUT=true : C[b][n][m] (time-major out, ldc = m-stride of a t-row)
// TOUT=false: C[b][m][n] (+bias[m])
// Block: 256 thr = 4 waves; tile M=64 x N=128 (wave: 64x32). No LDS.
template <bool TOUT, typename OutT>
__global__ __launch_bounds__(256) void gemm_mfma(
    const ushort_t* __restrict__ A, const ushort_t* __restrict__ BT,
    OutT* __restrict__ C, int K, long strideBT, long strideC, int ldc,
    const float* __restrict__ bias) {
  int lane = threadIdx.x & 63;
  int wave = threadIdx.x >> 6;
  int m0 = blockIdx.x * 64;
  long n0 = (long)blockIdx.y * 128 + wave * 32;
  int b = blockIdx.z;
  int r = lane & 15;
  int ko = (lane >> 4) * 8;
  const ushort_t* Ap = A + (size_t)(m0 + r) * K + ko;
  const ushort_t* Bp = BT + (size_t)b * strideBT + (size_t)(n0 + r) * K + ko;

  f32x4 acc[4][2];
  #pragma unroll
  for (int mi = 0; mi < 4; mi++)
    #pragma unroll
    for (int ni = 0; ni < 2; ni++) acc[mi][ni] = (f32x4){0.f, 0.f, 0.f, 0.f};

  for (int k0 = 0; k0 < K; k0 += 32) {
    bf16x8 fa[4], fb[2];
    #pragma unroll
    for (int mi = 0; mi < 4; mi++)
      fa[mi] = *(const bf16x8*)(Ap + (size_t)mi * 16 * K + k0);
    #pragma unroll
    for (int ni = 0; ni < 2; ni++)
      fb[ni] = *(const bf16x8*)(Bp + (size_t)ni * 16 * K + k0);
    #pragma unroll
    for (int mi = 0; mi < 4; mi++)
      #pragma unroll
      for (int ni = 0; ni < 2; ni++) {
        if constexpr (TOUT)
          acc[mi][ni] = __builtin_amdgcn_mfma_f32_16x16x32_bf16(fb[ni], fa[mi], acc[mi][ni], 0, 0, 0);
        else
          acc[mi][ni] = __builtin_amdgcn_mfma_f32_16x16x32_bf16(fa[mi], fb[ni], acc[mi][ni], 0, 0, 0);
      }
  }
  int cq = (lane >> 4) * 4;
  if constexpr (TOUT) {
    #pragma unroll
    for (int ni = 0; ni < 2; ni++)
      #pragma unroll
      for (int rg = 0; rg < 4; rg++) {
        long n = n0 + ni * 16 + cq + rg;
        OutT* cp = C + (size_t)b * strideC + n * ldc + m0 + (lane & 15);
        #pragma unroll
        for (int mi = 0; mi < 4; mi++) {
          float v = acc[mi][ni][rg];
          if constexpr (sizeof(OutT) == 2) cp[mi * 16] = f2bf(v);
          else                             cp[mi * 16] = v;
        }
      }
  } else {
    #pragma unroll
    for (int mi = 0; mi < 4; mi++)
      #pragma unroll
      for (int rg = 0; rg < 4; rg++) {
        int m = m0 + mi * 16 + cq + rg;
        float bv = bias ? bias[m] : 0.f;
        OutT* cp = C + (size_t)b * strideC + (size_t)m * ldc + n0 + (lane & 15);
        #pragma unroll
        for (int ni = 0; ni < 2; ni++)
          cp[ni * 16] = acc[mi][ni][rg] + bv;
      }
  }
}

// ---------------------------------------------------------------------------
// Conv: causal depthwise k=4 + bias + SiLU. Reads xzT u-half [t][0..383],
// writes u_t[b][t][d] bf16. Coalesced across d each t-step.
__global__ __launch_bounds__(128) void conv_silu_kernel(
    const ushort_t* __restrict__ xzT, const float* __restrict__ conv_w,
    const float* __restrict__ conv_b, ushort_t* __restrict__ u_t) {
  int tc = blockIdx.x, grp = blockIdx.y;
  int b = grp / 3;
  int d = (grp % 3) * 128 + threadIdx.x;
  int t0 = tc * 128;
  const ushort_t* xp = xzT + (size_t)b * LL * XZS + d;
  float w0 = conv_w[d * 4 + 0], w1 = conv_w[d * 4 + 1];
  float w2 = conv_w[d * 4 + 2], w3 = conv_w[d * 4 + 3];
  float cb = conv_b[d];
  float xm3 = (t0 >= 3) ? bf2f(xp[(size_t)(t0 - 3) * XZS]) : 0.f;
  float xm2 = (t0 >= 2) ? bf2f(xp[(size_t)(t0 - 2) * XZS]) : 0.f;
  float xm1 = (t0 >= 1) ? bf2f(xp[(size_t)(t0 - 1) * XZS]) : 0.f;
  ushort_t* up = u_t + ((size_t)b * LL + t0) * DI + d;
  for (int t = 0; t < 128; t++) {
    float xc = bf2f(xp[(size_t)(t0 + t) * XZS]);
    float a = cb + w3 * xc + w2 * xm1 + w1 * xm2 + w0 * xm3;
    float sv = a / (1.f + __expf(-a));
    up[(size_t)t * DI] = f2bf(sv);
    xm3 = xm2; xm2 = xm1; xm1 = xc;
  }
}

// ---------------------------------------------------------------------------
// dt_t[b][t][d] fp32 = softplus(dt_proj_w @ dblT[t][0..11] + dt_proj_b)
__global__ __launch_bounds__(384) void dt_kernel(
    const float* __restrict__ dblT, const float* __restrict__ dtw,
    const float* __restrict__ dtb, float* __restrict__ dt_t) {
  __shared__ float Ls[128 * 12];
  int t0 = blockIdx.x * 128;
  int b = blockIdx.y;
  int tid = threadIdx.x;
  for (int i = tid; i < 128 * 12; i += 384) {
    int t = i / 12, rr = i - t * 12;
    Ls[t * 12 + rr] = dblT[((size_t)b * LL + t0 + t) * DBS + rr];
  }
  float dw[12];
  #pragma unroll
  for (int rr = 0; rr < 12; rr += 4)
    *(float4*)(dw + rr) = *(const float4*)(dtw + tid * 12 + rr);
  float db = dtb[tid];
  __syncthreads();
  float* op = dt_t + ((size_t)b * LL + t0) * DI + tid;
  for (int t = 0; t < 128; t++) {
    float acc = db;
    #pragma unroll
    for (int rr = 0; rr < 12; rr++) acc = fmaf(Ls[t * 12 + rr], dw[rr], acc);
    float v = (acc > 20.f) ? acc : log1pf(__expf(acc));
    op[(size_t)t * DI] = v;
  }
}

// ---------------------------------------------------------------------------
// Scan phase 1: block=(chunk,b), 768 thr = pair (d, half), 8 states/thread.
__global__ __launch_bounds__(768) void scan_phase1(
    const float* __restrict__ dt_t, const ushort_t* __restrict__ u_t,
    const float* __restrict__ dblT, const float* __restrict__ A_log,
    float* __restrict__ hend, float* __restrict__ Pbuf) {
  __shared__ __align__(16) float Bs[CLEN * 20];
  int tid = threadIdx.x;
  int chunk = blockIdx.x, b = blockIdx.y;
  int t0 = chunk * CLEN;
  for (int i = tid; i < CLEN * NST; i += 768) {
    int t = i >> 4, s = i & 15;
    Bs[t * 20 + s] = dblT[((size_t)b * LL + t0 + t) * DBS + RDT + s];
  }
  int d = tid >> 1, half = tid & 1, s0 = half * 8;
  int bd = b * DI + d;
  float av0 = -expf(A_log[d * NST]);
  float av_[8];
  bool ok = true;
  #pragma unroll
  for (int j = 0; j < 8; j++) {
    av_[j] = -expf(A_log[d * NST + s0 + j]);
    ok = ok && (fabsf(av_[j] - av0 * (float)(s0 + j + 1)) <= 1e-4f * fabsf(av_[j]));
  }
  __syncthreads();
  const float* dtp = dt_t + ((size_t)b * LL + t0) * DI + d;
  const ushort_t* up = u_t + ((size_t)b * LL + t0) * DI + d;
  float h[8];
  #pragma unroll
  for (int j = 0; j < 8; j++) h[j] = 0.f;
  float S = 0.f;

  if (__all(ok)) {
    for (int t = 0; t < CLEN; t++) {
      float dtv = dtp[(size_t)t * DI];
      float uv  = bf2f(up[(size_t)t * DI]);
      float q = dtv * uv;
      S += dtv;
      float w  = __expf(dtv * av0);
      float dA = __expf(dtv * av_[0]);
      float4 B0 = *(const float4*)(&Bs[t * 20 + s0]);
      float4 B1 = *(const float4*)(&Bs[t * 20 + s0 + 4]);
      h[0] = dA * h[0] + q * B0.x; dA *= w;
      h[1] = dA * h[1] + q * B0.y; dA *= w;
      h[2] = dA * h[2] + q * B0.z; dA *= w;
      h[3] = dA * h[3] + q * B0.w; dA *= w;
      h[4] = dA * h[4] + q * B1.x; dA *= w;
      h[5] = dA * h[5] + q * B1.y; dA *= w;
      h[6] = dA * h[6] + q * B1.z; dA *= w;
      h[7] = dA * h[7] + q * B1.w;
    }
    size_t o = ((size_t)bd * NC + chunk) * NST + s0;
    *(float4*)(hend + o)     = make_float4(h[0], h[1], h[2], h[3]);
    *(float4*)(hend + o + 4) = make_float4(h[4], h[5], h[6], h[7]);
    float p1 = __expf(S * av0);
    float pj = __expf(S * av_[0]);
    float P[8];
    #pragma unroll
    for (int j = 0; j < 8; j++) { P[j] = pj; pj *= p1; }
    *(float4*)(Pbuf + o)     = make_float4(P[0], P[1], P[2], P[3]);
    *(float4*)(Pbuf + o + 4) = make_float4(P[4], P[5], P[6], P[7]);
  } else {
    for (int t = 0; t < CLEN; t++) {
      float dtv = dtp[(size_t)t * DI];
      float uv  = bf2f(up[(size_t)t * DI]);
      float q = dtv * uv;
      S += dtv;
      #pragma unroll
      for (int j = 0; j < 8; j++)
        h[j] = __expf(dtv * av_[j]) * h[j] + q * Bs[t * 20 + s0 + j];
    }
    size_t o = ((size_t)bd * NC + chunk) * NST + s0;
    #pragma unroll
    for (int j = 0; j < 8; j++) {
      hend[o + j] = h[j];
      Pbuf[o + j] = __expf(S * av_[j]);
    }
  }
}

// Scan phase 2: serial combine across chunks.
__global__ __launch_bounds__(256) void scan_combine(
    float* __restrict__ hend, const float* __restrict__ Pbuf) {
  int idx = blockIdx.x * 256 + threadIdx.x;
  int lane = idx & 15;
  int bd = idx >> 4;
  float c = 0.f;
  for (int ch = 0; ch < NC; ch++) {
    size_t o = ((size_t)bd * NC + ch) * NST + lane;
    float p = Pbuf[o], he = hend[o];
    hend[o] = c;
    c = p * c + he;
  }
}

// Scan phase 3: replay with carry; ym_t[b][t][d] bf16 = (y + u*D) * silu(z).
__global__ __launch_bounds__(768) void scan_phase3(
    const float* __restrict__ dt_t, const ushort_t* __restrict__ u_t,
    const float* __restrict__ dblT, const float* __restrict__ A_log,
    const float* __restrict__ hin, const float* __restrict__ Dp,
    const ushort_t* __restrict__ xzT, ushort_t* __restrict__ ym_t) {
  __shared__ __align__(16) float Bs[CLEN * 20];
  __shared__ __align__(16) float Cs[CLEN * 20];
  int tid = threadIdx.x;
  int chunk = blockIdx.x, b = blockIdx.y;
  int t0 = chunk * CLEN;
  for (int i = tid; i < CLEN * 2 * NST; i += 768) {
    int t = i >> 5, s = i & 31;
    float v = dblT[((size_t)b * LL + t0 + t) * DBS + RDT + s];
    if (s < NST) Bs[t * 20 + s] = v;
    else         Cs[t * 20 + (s - NST)] = v;
  }
  int d = tid >> 1, half = tid & 1, s0 = half * 8;
  int bd = b * DI + d;
  float av0 = -expf(A_log[d * NST]);
  float av_[8];
  bool ok = true;
  #pragma unroll
  for (int j = 0; j < 8; j++) {
    av_[j] = -expf(A_log[d * NST + s0 + j]);
    ok = ok && (fabsf(av_[j] - av0 * (float)(s0 + j + 1)) <= 1e-4f * fabsf(av_[j]));
  }
  __syncthreads();
  const float* dtp = dt_t + ((size_t)b * LL + t0) * DI + d;
  const ushort_t* up = u_t + ((size_t)b * LL + t0) * DI + d;
  const ushort_t* zp = xzT + ((size_t)b * LL + t0) * XZS + DI + d;
  ushort_t* ymp = ym_t + ((size_t)b * LL + t0) * DI + d;

  float h[8];
  const float* hi = hin + ((size_t)bd * NC + chunk) * NST + s0;
  float4 h0 = *(const float4*)(hi);
  float4 h1 = *(const float4*)(hi + 4);
  h[0] = h0.x; h[1] = h0.y; h[2] = h0.z; h[3] = h0.w;
  h[4] = h1.x; h[5] = h1.y; h[6] = h1.z; h[7] = h1.w;
  float Dv = Dp[d];

  if (__all(ok)) {
    for (int t = 0; t < CLEN; t++) {
      float dtv = dtp[(size_t)t * DI];
      float uv  = bf2f(up[(size_t)t * DI]);
      float q = dtv * uv;
      float w  = __expf(dtv * av0);
      float dA = __expf(dtv * av_[0]);
      float4 B0 = *(const float4*)(&Bs[t * 20 + s0]);
      float4 B1 = *(const float4*)(&Bs[t * 20 + s0 + 4]);
      float4 C0 = *(const float4*)(&Cs[t * 20 + s0]);
      float4 C1 = *(const float4*)(&Cs[t * 20 + s0 + 4]);
      float y;
      h[0] = dA * h[0] + q * B0.x; y  = h[0] * C0.x; dA *= w;
      h[1] = dA * h[1] + q * B0.y; y += h[1] * C0.y; dA *= w;
      h[2] = dA * h[2] + q * B0.z; y += h[2] * C0.z; dA *= w;
      h[3] = dA * h[3] + q * B0.w; y += h[3] * C0.w; dA *= w;
      h[4] = dA * h[4] + q * B1.x; y += h[4] * C1.x; dA *= w;
      h[5] = dA * h[5] + q * B1.y; y += h[5] * C1.y; dA *= w;
      h[6] = dA * h[6] + q * B1.z; y += h[6] * C1.z; dA *= w;
      h[7] = dA * h[7] + q * B1.w; y += h[7] * C1.w;
      y += __shfl_xor(y, 1);
      float zv = bf2f(zp[(size_t)t * XZS]);
      float yv = (y + uv * Dv) * (zv / (1.f + __expf(-zv)));
      if (half == (t & 1)) ymp[(size_t)t * DI] = f2bf(yv);
    }
  } else {
    for (int t = 0; t < CLEN; t++) {
      float dtv = dtp[(size_t)t * DI];
      float uv  = bf2f(up[(size_t)t * DI]);
      float q = dtv * uv;
      float y = 0.f;
      #pragma unroll
      for (int j = 0; j < 8; j++) {
        h[j] = __expf(dtv * av_[j]) * h[j] + q * Bs[t * 20 + s0 + j];
        y += h[j] * Cs[t * 20 + s0 + j];
      }
      y += __shfl_xor(y, 1);
      float zv = bf2f(zp[(size_t)t * XZS]);
      float yv = (y + uv * Dv) * (zv / (1.f + __expf(-zv)));
      if (half == (t & 1)) ymp[(size_t)t * DI] = f2bf(yv);
    }
  }
}

// ---------------------------------------------------------------------------
extern "C" void kernel_launch(void* const* d_in, const int* in_sizes, int n_in,
                              void* d_out, int out_size, void* d_ws, size_t ws_size,
                              hipStream_t stream) {
  const float* x         = (const float*)d_in[0];
  const float* in_proj_w = (const float*)d_in[1];
  const float* conv_w    = (const float*)d_in[2];
  const float* conv_b    = (const float*)d_in[3];
  const float* x_proj_w  = (const float*)d_in[4];
  const float* dt_proj_w = (const float*)d_in[5];
  const float* dt_proj_b = (const float*)d_in[6];
  const float* A_log     = (const float*)d_in[7];
  const float* D_param   = (const float*)d_in[8];
  const float* out_proj_w= (const float*)d_in[9];
  const float* proj_w    = (const float*)d_in[10];
  const float* proj_b    = (const float*)d_in[11];
  float* out = (float*)d_out;

  // workspace layout (float units)
  float* w = (float*)d_ws;
  float*    mu     = w;                                   // 512
  float*    rstd   = w + 512;                             // 512
  float*    PW     = w + 1024;                            // 73,728
  ushort_t* PW_bf  = (ushort_t*)(w + 74752);              // 73,728 bf16 (36,864 f)
  ushort_t* ipw_bf = (ushort_t*)(w + 111616);             // 147,456 bf16 (73,728 f)
  ushort_t* xpw_bf = (ushort_t*)(w + 185344);             // 24,576 bf16 (12,288 f)
  ushort_t* xT     = (ushort_t*)(w + 197632);             // 6.29M bf16 (3,145,728 f)
  ushort_t* xzT    = (ushort_t*)(w + 3343360);            // 25.2M bf16 (12,582,912 f)
  ushort_t* u_t    = (ushort_t*)(w + 15926272);           // 12.6M bf16 (6,291,456 f)
  float*    dblT   = w + 22217728;                        // 2,097,152 f
  float*    dt_t   = w + 24314880;                        // 12,582,912 f
  ushort_t* ym_t   = (ushort_t*)(w + 36897792);           // 12.6M bf16 (6,291,456 f)
  float*    hend   = w + 43189248;                        // 3,145,728 f
  float*    Pbuf   = w + 46334976;                        // 3,145,728 f
  size_t need = 49480704;
  if (ws_size < need * sizeof(float)) return;

  norm_stats_kernel<<<dim3(BB * CM), dim3(256), 0, stream>>>(x, mu, rstd);
  fuse_proj_kernel<<<dim3((CM * DI + 255) / 256), dim3(256), 0, stream>>>(proj_w, out_proj_w, PW);
  cvt_weights_kernel<<<dim3((2 * DI * CM + 255) / 256), dim3(256), 0, stream>>>(
      in_proj_w, x_proj_w, PW, ipw_bf, xpw_bf, PW_bf);
  xt_norm_kernel<<<dim3(LL / 64, CM / 64, BB), dim3(256), 0, stream>>>(x, mu, rstd, xT);

  // GEMM1: xzT[b][t][768] = xT(BT) x in_proj_w   (M=768, K=192)
  gemm_mfma<true, ushort_t><<<dim3(12, 128, BB), dim3(256), 0, stream>>>(
      ipw_bf, xT, xzT, CM, (long)LL * CM, (long)LL * XZS, XZS, nullptr);

  conv_silu_kernel<<<dim3(LL / 128, 6), dim3(128), 0, stream>>>(xzT, conv_w, conv_b, u_t);

  // GEMM2: dblT[b][t][64] = u_t(BT) x x_proj_w(padded)  (M=64, K=384)
  gemm_mfma<true, float><<<dim3(1, 128, BB), dim3(256), 0, stream>>>(
      xpw_bf, u_t, dblT, DI, (long)LL * DI, (long)LL * DBS, DBS, nullptr);

  dt_kernel<<<dim3(LL / 128, BB), dim3(384), 0, stream>>>(dblT, dt_proj_w, dt_proj_b, dt_t);

  scan_phase1<<<dim3(NC, BB), dim3(768), 0, stream>>>(dt_t, u_t, dblT, A_log, hend, Pbuf);
  scan_combine<<<dim3(BB * DI * NST / 256), dim3(256), 0, stream>>>(hend, Pbuf);
  scan_phase3<<<dim3(NC, BB), dim3(768), 0, stream>>>(dt_t, u_t, dblT, A_log, hend, D_param, xzT, ym_t);

  // GEMM3: out[b][192][L] = PW x ym_t(BT) + proj_b  (M=192, K=384)
  gemm_mfma<false, float><<<dim3(3, 128, BB), dim3(256), 0, stream>>>(
      PW_bf, ym_t, out, DI, (long)LL * DI, (long)CM * LL, LL, proj_b);
}

// Round 5
// 284.783 us; speedup vs baseline: 8.5596x; 1.2154x over previous
//
#include <hip/hip_runtime.h>
#include <hip/hip_bf16.h>
#include <math.h>

// Problem constants
#define BB   2
#define CM   192        // D_MODEL
#define DI   384        // D_INNER
#define LL   16384      // D*H*W
#define NST  16         // D_STATE
#define RDT  12         // DT_RANK
#define XJ   44         // DT_RANK + 2*D_STATE
#define NC   256        // scan chunks
#define CLEN 64         // chunk length
#define DBS  64         // dblT row stride (GEMM2 padded M)
#define XZS  768        // xzT row stride
#define CVT  32         // conv t-tile
#define DTT  32         // dt t-tile

typedef __attribute__((ext_vector_type(8))) short bf16x8;
typedef __attribute__((ext_vector_type(4))) float f32x4;
typedef unsigned short ushort_t;

static __device__ __forceinline__ ushort_t f2bf(float f) {
  __hip_bfloat16 h = __float2bfloat16(f);
  return *reinterpret_cast<ushort_t*>(&h);
}
static __device__ __forceinline__ float bf2f(ushort_t u) {
  __hip_bfloat16 h;
  *reinterpret_cast<ushort_t*>(&h) = u;
  return __bfloat162float(h);
}

// ---------------------------------------------------------------------------
// PW = proj_w(192x192) @ out_proj_w(192x384)   (fp32, tiny)
__global__ __launch_bounds__(256) void fuse_proj_kernel(
    const float* __restrict__ pw, const float* __restrict__ ow, float* __restrict__ PW) {
  int idx = blockIdx.x * 256 + threadIdx.x;
  if (idx >= CM * DI) return;
  int o = idx / DI, d = idx % DI;
  float s = 0.f;
  #pragma unroll 4
  for (int c = 0; c < CM; c++) s += pw[o * CM + c] * ow[c * DI + d];
  PW[idx] = s;
}

// ---------------------------------------------------------------------------
// Weight conversions to bf16 (x_proj padded 44 -> 64 rows with zeros)
__global__ __launch_bounds__(256) void cvt_weights_kernel(
    const float* __restrict__ ipw, const float* __restrict__ xpw,
    const float* __restrict__ PW,
    ushort_t* __restrict__ ipw_bf, ushort_t* __restrict__ xpw_bf,
    ushort_t* __restrict__ PW_bf) {
  int i = blockIdx.x * 256 + threadIdx.x;
  if (i < 2 * DI * CM) ipw_bf[i] = f2bf(ipw[i]);          // 768x192
  if (i < DBS * DI) {                                      // 64x384 (pad)
    int r = i / DI;
    xpw_bf[i] = (r < XJ) ? f2bf(xpw[i]) : (ushort_t)0;
  }
  if (i < CM * DI) PW_bf[i] = f2bf(PW[i]);                 // 192x384
}

// ---------------------------------------------------------------------------
// per-(b,c) mean / rstd over L
__global__ __launch_bounds__(256) void norm_stats_kernel(
    const float* __restrict__ x, float* __restrict__ mu, float* __restrict__ rstd) {
  int bc = blockIdx.x;
  const float* p = x + (size_t)bc * LL;
  float s = 0.f, ss = 0.f;
  for (int i = threadIdx.x * 4; i < LL; i += 256 * 4) {
    float4 v = *(const float4*)(p + i);
    s += v.x + v.y + v.z + v.w;
    ss += v.x * v.x + v.y * v.y + v.z * v.z + v.w * v.w;
  }
  for (int o = 32; o > 0; o >>= 1) {
    s += __shfl_down(s, o, 64);
    ss += __shfl_down(ss, o, 64);
  }
  __shared__ float sb[4], ssb[4];
  int wid = threadIdx.x >> 6;
  if ((threadIdx.x & 63) == 0) { sb[wid] = s; ssb[wid] = ss; }
  __syncthreads();
  if (threadIdx.x == 0) {
    s = sb[0] + sb[1] + sb[2] + sb[3];
    ss = ssb[0] + ssb[1] + ssb[2] + ssb[3];
    float m = s * (1.f / LL);
    float var = ss * (1.f / LL) - m * m;
    mu[bc] = m;
    rstd[bc] = 1.f / sqrtf(var + 1e-5f);
  }
}

// ---------------------------------------------------------------------------
// xT[b][t][c] bf16 = normalized x (LDS 64x64 transpose tile)
__global__ __launch_bounds__(256) void xt_norm_kernel(
    const float* __restrict__ x, const float* __restrict__ mu,
    const float* __restrict__ rstd, ushort_t* __restrict__ xT) {
  __shared__ ushort_t T[64][72];
  int t0 = blockIdx.x * 64, c0 = blockIdx.y * 64, b = blockIdx.z;
  int tid = threadIdx.x;
  int c = tid >> 2, tq = (tid & 3) * 16;
  int bc = b * CM + c0 + c;
  const float* xp = x + (size_t)bc * LL + t0 + tq;
  float m = mu[bc], rs = rstd[bc];
  #pragma unroll
  for (int j = 0; j < 16; j += 4) {
    float4 v = *(const float4*)(xp + j);
    T[c][tq + j + 0] = f2bf((v.x - m) * rs);
    T[c][tq + j + 1] = f2bf((v.y - m) * rs);
    T[c][tq + j + 2] = f2bf((v.z - m) * rs);
    T[c][tq + j + 3] = f2bf((v.w - m) * rs);
  }
  __syncthreads();
  int t = tid >> 2, cq = (tid & 3) * 16;
  unsigned int ob[8];
  #pragma unroll
  for (int j = 0; j < 8; j++)
    ob[j] = (unsigned int)T[cq + 2 * j][t] | ((unsigned int)T[cq + 2 * j + 1][t] << 16);
  ushort_t* op = xT + ((size_t)b * LL + t0 + t) * CM + c0 + cq;
  *(uint4*)(op)     = make_uint4(ob[0], ob[1], ob[2], ob[3]);
  *(uint4*)(op + 8) = make_uint4(ob[4], ob[5], ob[6], ob[7]);
}

// ---------------------------------------------------------------------------
// MFMA bf16 GEMM.  A[Mp][K] bf16 row-major (weights, Mp mult of 64).
// BT[b][N][K] bf16 row-major (activations, time-major).
// TOUT=true : C[b][n][m] (time-major out, ldc = m-stride of a t-row)
// TOUT=false: C[b][m][n] (+bias[m])
// Block: 256 thr = 4 waves; tile M=64 x N=128 (wave: 64x32). No LDS.
template <bool TOUT, typename OutT>
__global__ __launch_bounds__(256) void gemm_mfma(
    const ushort_t* __restrict__ A, const ushort_t* __restrict__ BT,
    OutT* __restrict__ C, int K, long strideBT, long strideC, int ldc,
    const float* __restrict__ bias) {
  int lane = threadIdx.x & 63;
  int wave = threadIdx.x >> 6;
  int m0 = blockIdx.x * 64;
  long n0 = (long)blockIdx.y * 128 + wave * 32;
  int b = blockIdx.z;
  int r = lane & 15;
  int ko = (lane >> 4) * 8;
  const ushort_t* Ap = A + (size_t)(m0 + r) * K + ko;
  const ushort_t* Bp = BT + (size_t)b * strideBT + (size_t)(n0 + r) * K + ko;

  f32x4 acc[4][2];
  #pragma unroll
  for (int mi = 0; mi < 4; mi++)
    #pragma unroll
    for (int ni = 0; ni < 2; ni++) acc[mi][ni] = (f32x4){0.f, 0.f, 0.f, 0.f};

  for (int k0 = 0; k0 < K; k0 += 32) {
    bf16x8 fa[4], fb[2];
    #pragma unroll
    for (int mi = 0; mi < 4; mi++)
      fa[mi] = *(const bf16x8*)(Ap + (size_t)mi * 16 * K + k0);
    #pragma unroll
    for (int ni = 0; ni < 2; ni++)
      fb[ni] = *(const bf16x8*)(Bp + (size_t)ni * 16 * K + k0);
    #pragma unroll
    for (int mi = 0; mi < 4; mi++)
      #pragma unroll
      for (int ni = 0; ni < 2; ni++) {
        if constexpr (TOUT)
          acc[mi][ni] = __builtin_amdgcn_mfma_f32_16x16x32_bf16(fb[ni], fa[mi], acc[mi][ni], 0, 0, 0);
        else
          acc[mi][ni] = __builtin_amdgcn_mfma_f32_16x16x32_bf16(fa[mi], fb[ni], acc[mi][ni], 0, 0, 0);
      }
  }
  int cq = (lane >> 4) * 4;
  if constexpr (TOUT) {
    #pragma unroll
    for (int ni = 0; ni < 2; ni++)
      #pragma unroll
      for (int rg = 0; rg < 4; rg++) {
        long n = n0 + ni * 16 + cq + rg;
        OutT* cp = C + (size_t)b * strideC + n * ldc + m0 + (lane & 15);
        #pragma unroll
        for (int mi = 0; mi < 4; mi++) {
          float v = acc[mi][ni][rg];
          if constexpr (sizeof(OutT) == 2) cp[mi * 16] = f2bf(v);
          else                             cp[mi * 16] = v;
        }
      }
  } else {
    #pragma unroll
    for (int mi = 0; mi < 4; mi++)
      #pragma unroll
      for (int rg = 0; rg < 4; rg++) {
        int m = m0 + mi * 16 + cq + rg;
        float bv = bias ? bias[m] : 0.f;
        OutT* cp = C + (size_t)b * strideC + (size_t)m * ldc + n0 + (lane & 15);
        #pragma unroll
        for (int ni = 0; ni < 2; ni++)
          cp[ni * 16] = acc[mi][ni][rg] + bv;
      }
  }
}

// ---------------------------------------------------------------------------
// Conv: causal depthwise k=4 + bias + SiLU.  LDS-staged xzT u-half rows
// (coalesced), 32 t per block, all 384 d. Writes u_t[b][t][d] bf16.
__global__ __launch_bounds__(384) void conv_silu_kernel(
    const ushort_t* __restrict__ xzT, const float* __restrict__ conv_w,
    const float* __restrict__ conv_b, ushort_t* __restrict__ u_t) {
  __shared__ ushort_t Us[CVT + 3][DI];
  int t0 = blockIdx.x * CVT;
  int b = blockIdx.y;
  int tid = threadIdx.x;          // d
  #pragma unroll
  for (int r = 0; r < CVT + 3; r++) {
    int t = t0 - 3 + r;
    Us[r][tid] = (t >= 0) ? xzT[((size_t)b * LL + t) * XZS + tid] : (ushort_t)0;
  }
  float w0 = conv_w[tid * 4 + 0], w1 = conv_w[tid * 4 + 1];
  float w2 = conv_w[tid * 4 + 2], w3 = conv_w[tid * 4 + 3];
  float cb = conv_b[tid];
  __syncthreads();
  ushort_t* up = u_t + ((size_t)b * LL + t0) * DI + tid;
  float xm3 = bf2f(Us[0][tid]);
  float xm2 = bf2f(Us[1][tid]);
  float xm1 = bf2f(Us[2][tid]);
  #pragma unroll
  for (int t = 0; t < CVT; t++) {
    float xc = bf2f(Us[t + 3][tid]);
    float a = cb + w3 * xc + w2 * xm1 + w1 * xm2 + w0 * xm3;
    float sv = a / (1.f + __expf(-a));
    up[(size_t)t * DI] = f2bf(sv);
    xm3 = xm2; xm2 = xm1; xm1 = xc;
  }
}

// ---------------------------------------------------------------------------
// dt_t[b][t][d] fp32 = softplus(dt_proj_w @ dblT[t][0..11] + dt_proj_b)
// 32 t per block, LDS-staged dt_low, fast softplus.
__global__ __launch_bounds__(384) void dt_kernel(
    const float* __restrict__ dblT, const float* __restrict__ dtw,
    const float* __restrict__ dtb, float* __restrict__ dt_t) {
  __shared__ float Ls[DTT * 12];
  int t0 = blockIdx.x * DTT;
  int b = blockIdx.y;
  int tid = threadIdx.x;          // d
  if (tid < DTT * 12) {
    int t = tid / 12, rr = tid - t * 12;
    Ls[tid] = dblT[((size_t)b * LL + t0 + t) * DBS + rr];
  }
  float dw[12];
  #pragma unroll
  for (int rr = 0; rr < 12; rr += 4)
    *(float4*)(dw + rr) = *(const float4*)(dtw + tid * 12 + rr);
  float db = dtb[tid];
  __syncthreads();
  float* op = dt_t + ((size_t)b * LL + t0) * DI + tid;
  #pragma unroll
  for (int t = 0; t < DTT; t++) {
    float acc = db;
    #pragma unroll
    for (int rr = 0; rr < 12; rr++) acc = fmaf(Ls[t * 12 + rr], dw[rr], acc);
    float v = (acc > 15.f) ? acc : __logf(1.f + __expf(acc));
    op[(size_t)t * DI] = v;
  }
}

// ---------------------------------------------------------------------------
// Scan phase 1: block=(chunk,b), 768 thr = pair (d, half), 8 states/thread.
__global__ __launch_bounds__(768) void scan_phase1(
    const float* __restrict__ dt_t, const ushort_t* __restrict__ u_t,
    const float* __restrict__ dblT, const float* __restrict__ A_log,
    float* __restrict__ hend, float* __restrict__ Pbuf) {
  __shared__ __align__(16) float Bs[CLEN * 20];
  int tid = threadIdx.x;
  int chunk = blockIdx.x, b = blockIdx.y;
  int t0 = chunk * CLEN;
  for (int i = tid; i < CLEN * NST; i += 768) {
    int t = i >> 4, s = i & 15;
    Bs[t * 20 + s] = dblT[((size_t)b * LL + t0 + t) * DBS + RDT + s];
  }
  int d = tid >> 1, half = tid & 1, s0 = half * 8;
  int bd = b * DI + d;
  float av0 = -expf(A_log[d * NST]);
  float av_[8];
  bool ok = true;
  #pragma unroll
  for (int j = 0; j < 8; j++) {
    av_[j] = -expf(A_log[d * NST + s0 + j]);
    ok = ok && (fabsf(av_[j] - av0 * (float)(s0 + j + 1)) <= 1e-4f * fabsf(av_[j]));
  }
  __syncthreads();
  const float* dtp = dt_t + ((size_t)b * LL + t0) * DI + d;
  const ushort_t* up = u_t + ((size_t)b * LL + t0) * DI + d;
  float h[8];
  #pragma unroll
  for (int j = 0; j < 8; j++) h[j] = 0.f;
  float S = 0.f;

  if (__all(ok)) {
    for (int t = 0; t < CLEN; t++) {
      float dtv = dtp[(size_t)t * DI];
      float uv  = bf2f(up[(size_t)t * DI]);
      float q = dtv * uv;
      S += dtv;
      float w  = __expf(dtv * av0);
      float dA = __expf(dtv * av_[0]);
      float4 B0 = *(const float4*)(&Bs[t * 20 + s0]);
      float4 B1 = *(const float4*)(&Bs[t * 20 + s0 + 4]);
      h[0] = dA * h[0] + q * B0.x; dA *= w;
      h[1] = dA * h[1] + q * B0.y; dA *= w;
      h[2] = dA * h[2] + q * B0.z; dA *= w;
      h[3] = dA * h[3] + q * B0.w; dA *= w;
      h[4] = dA * h[4] + q * B1.x; dA *= w;
      h[5] = dA * h[5] + q * B1.y; dA *= w;
      h[6] = dA * h[6] + q * B1.z; dA *= w;
      h[7] = dA * h[7] + q * B1.w;
    }
    size_t o = ((size_t)bd * NC + chunk) * NST + s0;
    *(float4*)(hend + o)     = make_float4(h[0], h[1], h[2], h[3]);
    *(float4*)(hend + o + 4) = make_float4(h[4], h[5], h[6], h[7]);
    float p1 = __expf(S * av0);
    float pj = __expf(S * av_[0]);
    float P[8];
    #pragma unroll
    for (int j = 0; j < 8; j++) { P[j] = pj; pj *= p1; }
    *(float4*)(Pbuf + o)     = make_float4(P[0], P[1], P[2], P[3]);
    *(float4*)(Pbuf + o + 4) = make_float4(P[4], P[5], P[6], P[7]);
  } else {
    for (int t = 0; t < CLEN; t++) {
      float dtv = dtp[(size_t)t * DI];
      float uv  = bf2f(up[(size_t)t * DI]);
      float q = dtv * uv;
      S += dtv;
      #pragma unroll
      for (int j = 0; j < 8; j++)
        h[j] = __expf(dtv * av_[j]) * h[j] + q * Bs[t * 20 + s0 + j];
    }
    size_t o = ((size_t)bd * NC + chunk) * NST + s0;
    #pragma unroll
    for (int j = 0; j < 8; j++) {
      hend[o + j] = h[j];
      Pbuf[o + j] = __expf(S * av_[j]);
    }
  }
}

// Scan phase 2: serial combine across chunks.
__global__ __launch_bounds__(256) void scan_combine(
    float* __restrict__ hend, const float* __restrict__ Pbuf) {
  int idx = blockIdx.x * 256 + threadIdx.x;
  int lane = idx & 15;
  int bd = idx >> 4;
  float c = 0.f;
  for (int ch = 0; ch < NC; ch++) {
    size_t o = ((size_t)bd * NC + ch) * NST + lane;
    float p = Pbuf[o], he = hend[o];
    hend[o] = c;
    c = p * c + he;
  }
}

// Scan phase 3: replay with carry; ym_t[b][t][d] bf16 = (y + u*D) * silu(z).
__global__ __launch_bounds__(768) void scan_phase3(
    const float* __restrict__ dt_t, const ushort_t* __restrict__ u_t,
    const float* __restrict__ dblT, const float* __restrict__ A_log,
    const float* __restrict__ hin, const float* __restrict__ Dp,
    const ushort_t* __restrict__ xzT, ushort_t* __restrict__ ym_t) {
  __shared__ __align__(16) float Bs[CLEN * 20];
  __shared__ __align__(16) float Cs[CLEN * 20];
  int tid = threadIdx.x;
  int chunk = blockIdx.x, b = blockIdx.y;
  int t0 = chunk * CLEN;
  for (int i = tid; i < CLEN * 2 * NST; i += 768) {
    int t = i >> 5, s = i & 31;
    float v = dblT[((size_t)b * LL + t0 + t) * DBS + RDT + s];
    if (s < NST) Bs[t * 20 + s] = v;
    else         Cs[t * 20 + (s - NST)] = v;
  }
  int d = tid >> 1, half = tid & 1, s0 = half * 8;
  int bd = b * DI + d;
  float av0 = -expf(A_log[d * NST]);
  float av_[8];
  bool ok = true;
  #pragma unroll
  for (int j = 0; j < 8; j++) {
    av_[j] = -expf(A_log[d * NST + s0 + j]);
    ok = ok && (fabsf(av_[j] - av0 * (float)(s0 + j + 1)) <= 1e-4f * fabsf(av_[j]));
  }
  __syncthreads();
  const float* dtp = dt_t + ((size_t)b * LL + t0) * DI + d;
  const ushort_t* up = u_t + ((size_t)b * LL + t0) * DI + d;
  const ushort_t* zp = xzT + ((size_t)b * LL + t0) * XZS + DI + d;
  ushort_t* ymp = ym_t + ((size_t)b * LL + t0) * DI + d;

  float h[8];
  const float* hi = hin + ((size_t)bd * NC + chunk) * NST + s0;
  float4 h0 = *(const float4*)(hi);
  float4 h1 = *(const float4*)(hi + 4);
  h[0] = h0.x; h[1] = h0.y; h[2] = h0.z; h[3] = h0.w;
  h[4] = h1.x; h[5] = h1.y; h[6] = h1.z; h[7] = h1.w;
  float Dv = Dp[d];

  if (__all(ok)) {
    for (int t = 0; t < CLEN; t++) {
      float dtv = dtp[(size_t)t * DI];
      float uv  = bf2f(up[(size_t)t * DI]);
      float q = dtv * uv;
      float w  = __expf(dtv * av0);
      float dA = __expf(dtv * av_[0]);
      float4 B0 = *(const float4*)(&Bs[t * 20 + s0]);
      float4 B1 = *(const float4*)(&Bs[t * 20 + s0 + 4]);
      float4 C0 = *(const float4*)(&Cs[t * 20 + s0]);
      float4 C1 = *(const float4*)(&Cs[t * 20 + s0 + 4]);
      float y;
      h[0] = dA * h[0] + q * B0.x; y  = h[0] * C0.x; dA *= w;
      h[1] = dA * h[1] + q * B0.y; y += h[1] * C0.y; dA *= w;
      h[2] = dA * h[2] + q * B0.z; y += h[2] * C0.z; dA *= w;
      h[3] = dA * h[3] + q * B0.w; y += h[3] * C0.w; dA *= w;
      h[4] = dA * h[4] + q * B1.x; y += h[4] * C1.x; dA *= w;
      h[5] = dA * h[5] + q * B1.y; y += h[5] * C1.y; dA *= w;
      h[6] = dA * h[6] + q * B1.z; y += h[6] * C1.z; dA *= w;
      h[7] = dA * h[7] + q * B1.w; y += h[7] * C1.w;
      y += __shfl_xor(y, 1);
      float zv = bf2f(zp[(size_t)t * XZS]);
      float yv = (y + uv * Dv) * (zv / (1.f + __expf(-zv)));
      if (half == (t & 1)) ymp[(size_t)t * DI] = f2bf(yv);
    }
  } else {
    for (int t = 0; t < CLEN; t++) {
      float dtv = dtp[(size_t)t * DI];
      float uv  = bf2f(up[(size_t)t * DI]);
      float q = dtv * uv;
      float y = 0.f;
      #pragma unroll
      for (int j = 0; j < 8; j++) {
        h[j] = __expf(dtv * av_[j]) * h[j] + q * Bs[t * 20 + s0 + j];
        y += h[j] * Cs[t * 20 + s0 + j];
      }
      y += __shfl_xor(y, 1);
      float zv = bf2f(zp[(size_t)t * XZS]);
      float yv = (y + uv * Dv) * (zv / (1.f + __expf(-zv)));
      if (half == (t & 1)) ymp[(size_t)t * DI] = f2bf(yv);
    }
  }
}

// ---------------------------------------------------------------------------
extern "C" void kernel_launch(void* const* d_in, const int* in_sizes, int n_in,
                              void* d_out, int out_size, void* d_ws, size_t ws_size,
                              hipStream_t stream) {
  const float* x         = (const float*)d_in[0];
  const float* in_proj_w = (const float*)d_in[1];
  const float* conv_w    = (const float*)d_in[2];
  const float* conv_b    = (const float*)d_in[3];
  const float* x_proj_w  = (const float*)d_in[4];
  const float* dt_proj_w = (const float*)d_in[5];
  const float* dt_proj_b = (const float*)d_in[6];
  const float* A_log     = (const float*)d_in[7];
  const float* D_param   = (const float*)d_in[8];
  const float* out_proj_w= (const float*)d_in[9];
  const float* proj_w    = (const float*)d_in[10];
  const float* proj_b    = (const float*)d_in[11];
  float* out = (float*)d_out;

  // workspace layout (float units)
  float* w = (float*)d_ws;
  float*    mu     = w;                                   // 512
  float*    rstd   = w + 512;                             // 512
  float*    PW     = w + 1024;                            // 73,728
  ushort_t* PW_bf  = (ushort_t*)(w + 74752);              // 73,728 bf16 (36,864 f)
  ushort_t* ipw_bf = (ushort_t*)(w + 111616);             // 147,456 bf16 (73,728 f)
  ushort_t* xpw_bf = (ushort_t*)(w + 185344);             // 24,576 bf16 (12,288 f)
  ushort_t* xT     = (ushort_t*)(w + 197632);             // 6.29M bf16 (3,145,728 f)
  ushort_t* xzT    = (ushort_t*)(w + 3343360);            // 25.2M bf16 (12,582,912 f)
  ushort_t* u_t    = (ushort_t*)(w + 15926272);           // 12.6M bf16 (6,291,456 f)
  float*    dblT   = w + 22217728;                        // 2,097,152 f
  float*    dt_t   = w + 24314880;                        // 12,582,912 f
  ushort_t* ym_t   = (ushort_t*)(w + 36897792);           // 12.6M bf16 (6,291,456 f)
  float*    hend   = w + 43189248;                        // 3,145,728 f
  float*    Pbuf   = w + 46334976;                        // 3,145,728 f
  size_t need = 49480704;
  if (ws_size < need * sizeof(float)) return;

  norm_stats_kernel<<<dim3(BB * CM), dim3(256), 0, stream>>>(x, mu, rstd);
  fuse_proj_kernel<<<dim3((CM * DI + 255) / 256), dim3(256), 0, stream>>>(proj_w, out_proj_w, PW);
  cvt_weights_kernel<<<dim3((2 * DI * CM + 255) / 256), dim3(256), 0, stream>>>(
      in_proj_w, x_proj_w, PW, ipw_bf, xpw_bf, PW_bf);
  xt_norm_kernel<<<dim3(LL / 64, CM / 64, BB), dim3(256), 0, stream>>>(x, mu, rstd, xT);

  // GEMM1: xzT[b][t][768] = xT(BT) x in_proj_w   (M=768, K=192)
  gemm_mfma<true, ushort_t><<<dim3(12, 128, BB), dim3(256), 0, stream>>>(
      ipw_bf, xT, xzT, CM, (long)LL * CM, (long)LL * XZS, XZS, nullptr);

  conv_silu_kernel<<<dim3(LL / CVT, BB), dim3(384), 0, stream>>>(xzT, conv_w, conv_b, u_t);

  // GEMM2: dblT[b][t][64] = u_t(BT) x x_proj_w(padded)  (M=64, K=384)
  gemm_mfma<true, float><<<dim3(1, 128, BB), dim3(256), 0, stream>>>(
      xpw_bf, u_t, dblT, DI, (long)LL * DI, (long)LL * DBS, DBS, nullptr);

  dt_kernel<<<dim3(LL / DTT, BB), dim3(384), 0, stream>>>(dblT, dt_proj_w, dt_proj_b, dt_t);

  scan_phase1<<<dim3(NC, BB), dim3(768), 0, stream>>>(dt_t, u_t, dblT, A_log, hend, Pbuf);
  scan_combine<<<dim3(BB * DI * NST / 256), dim3(256), 0, stream>>>(hend, Pbuf);
  scan_phase3<<<dim3(NC, BB), dim3(768), 0, stream>>>(dt_t, u_t, dblT, A_log, hend, D_param, xzT, ym_t);

  // GEMM3: out[b][192][L] = PW x ym_t(BT) + proj_b  (M=192, K=384)
  gemm_mfma<false, float><<<dim3(3, 128, BB), dim3(256), 0, stream>>>(
      PW_bf, ym_t, out, DI, (long)LL * DI, (long)CM * LL, LL, proj_b);
}

// Round 6
// 270.761 us; speedup vs baseline: 9.0029x; 1.0518x over previous
//
#include <hip/hip_runtime.h>
#include <hip/hip_bf16.h>
#include <math.h>

// Problem constants
#define BB   2
#define CM   192        // D_MODEL
#define DI   384        // D_INNER
#define LL   16384      // D*H*W
#define NST  16         // D_STATE
#define RDT  12         // DT_RANK
#define XJ   44         // DT_RANK + 2*D_STATE
#define NC   256        // scan chunks
#define CLEN 64         // chunk length
#define DBS  64         // dblT row stride (GEMM2 padded M)
#define XZS  768        // xzT row stride
#define CVT  32         // conv t-tile
#define DTT  32         // dt t-tile

typedef __attribute__((ext_vector_type(8))) short bf16x8;
typedef __attribute__((ext_vector_type(4))) float f32x4;
typedef unsigned short ushort_t;

static __device__ __forceinline__ ushort_t f2bf(float f) {
  __hip_bfloat16 h = __float2bfloat16(f);
  return *reinterpret_cast<ushort_t*>(&h);
}
static __device__ __forceinline__ float bf2f(ushort_t u) {
  __hip_bfloat16 h;
  *reinterpret_cast<ushort_t*>(&h) = u;
  return __bfloat162float(h);
}

// ---------------------------------------------------------------------------
// PW = proj_w(192x192) @ out_proj_w(192x384)   (fp32, tiny)
__global__ __launch_bounds__(256) void fuse_proj_kernel(
    const float* __restrict__ pw, const float* __restrict__ ow, float* __restrict__ PW) {
  int idx = blockIdx.x * 256 + threadIdx.x;
  if (idx >= CM * DI) return;
  int o = idx / DI, d = idx % DI;
  float s = 0.f;
  #pragma unroll 4
  for (int c = 0; c < CM; c++) s += pw[o * CM + c] * ow[c * DI + d];
  PW[idx] = s;
}

// ---------------------------------------------------------------------------
// Weight conversions to bf16 (x_proj padded 44 -> 64 rows with zeros)
__global__ __launch_bounds__(256) void cvt_weights_kernel(
    const float* __restrict__ ipw, const float* __restrict__ xpw,
    const float* __restrict__ PW,
    ushort_t* __restrict__ ipw_bf, ushort_t* __restrict__ xpw_bf,
    ushort_t* __restrict__ PW_bf) {
  int i = blockIdx.x * 256 + threadIdx.x;
  if (i < 2 * DI * CM) ipw_bf[i] = f2bf(ipw[i]);          // 768x192
  if (i < DBS * DI) {                                      // 64x384 (pad)
    int r = i / DI;
    xpw_bf[i] = (r < XJ) ? f2bf(xpw[i]) : (ushort_t)0;
  }
  if (i < CM * DI) PW_bf[i] = f2bf(PW[i]);                 // 192x384
}

// ---------------------------------------------------------------------------
// per-(b,c) mean / rstd over L
__global__ __launch_bounds__(256) void norm_stats_kernel(
    const float* __restrict__ x, float* __restrict__ mu, float* __restrict__ rstd) {
  int bc = blockIdx.x;
  const float* p = x + (size_t)bc * LL;
  float s = 0.f, ss = 0.f;
  for (int i = threadIdx.x * 4; i < LL; i += 256 * 4) {
    float4 v = *(const float4*)(p + i);
    s += v.x + v.y + v.z + v.w;
    ss += v.x * v.x + v.y * v.y + v.z * v.z + v.w * v.w;
  }
  for (int o = 32; o > 0; o >>= 1) {
    s += __shfl_down(s, o, 64);
    ss += __shfl_down(ss, o, 64);
  }
  __shared__ float sb[4], ssb[4];
  int wid = threadIdx.x >> 6;
  if ((threadIdx.x & 63) == 0) { sb[wid] = s; ssb[wid] = ss; }
  __syncthreads();
  if (threadIdx.x == 0) {
    s = sb[0] + sb[1] + sb[2] + sb[3];
    ss = ssb[0] + ssb[1] + ssb[2] + ssb[3];
    float m = s * (1.f / LL);
    float var = ss * (1.f / LL) - m * m;
    mu[bc] = m;
    rstd[bc] = 1.f / sqrtf(var + 1e-5f);
  }
}

// ---------------------------------------------------------------------------
// xT[b][t][c] bf16 = normalized x (LDS 64x64 transpose tile)
__global__ __launch_bounds__(256) void xt_norm_kernel(
    const float* __restrict__ x, const float* __restrict__ mu,
    const float* __restrict__ rstd, ushort_t* __restrict__ xT) {
  __shared__ ushort_t T[64][72];
  int t0 = blockIdx.x * 64, c0 = blockIdx.y * 64, b = blockIdx.z;
  int tid = threadIdx.x;
  int c = tid >> 2, tq = (tid & 3) * 16;
  int bc = b * CM + c0 + c;
  const float* xp = x + (size_t)bc * LL + t0 + tq;
  float m = mu[bc], rs = rstd[bc];
  #pragma unroll
  for (int j = 0; j < 16; j += 4) {
    float4 v = *(const float4*)(xp + j);
    T[c][tq + j + 0] = f2bf((v.x - m) * rs);
    T[c][tq + j + 1] = f2bf((v.y - m) * rs);
    T[c][tq + j + 2] = f2bf((v.z - m) * rs);
    T[c][tq + j + 3] = f2bf((v.w - m) * rs);
  }
  __syncthreads();
  int t = tid >> 2, cq = (tid & 3) * 16;
  unsigned int ob[8];
  #pragma unroll
  for (int j = 0; j < 8; j++)
    ob[j] = (unsigned int)T[cq + 2 * j][t] | ((unsigned int)T[cq + 2 * j + 1][t] << 16);
  ushort_t* op = xT + ((size_t)b * LL + t0 + t) * CM + c0 + cq;
  *(uint4*)(op)     = make_uint4(ob[0], ob[1], ob[2], ob[3]);
  *(uint4*)(op + 8) = make_uint4(ob[4], ob[5], ob[6], ob[7]);
}

// ---------------------------------------------------------------------------
// MFMA bf16 GEMM.  A[Mp][K] bf16 row-major (weights, Mp mult of 64).
// BT[b][N][K] bf16 row-major (activations, time-major).
// TOUT=true : C[b][n][m] (time-major out, ldc = m-stride of a t-row)
// TOUT=false: C[b][m][n] (+bias[m])
// Block: 256 thr = 4 waves; tile M=64 x N=128 (wave: 64x32). No LDS.
template <bool TOUT, typename OutT>
__global__ __launch_bounds__(256) void gemm_mfma(
    const ushort_t* __restrict__ A, const ushort_t* __restrict__ BT,
    OutT* __restrict__ C, int K, long strideBT, long strideC, int ldc,
    const float* __restrict__ bias) {
  int lane = threadIdx.x & 63;
  int wave = threadIdx.x >> 6;
  int m0 = blockIdx.x * 64;
  long n0 = (long)blockIdx.y * 128 + wave * 32;
  int b = blockIdx.z;
  int r = lane & 15;
  int ko = (lane >> 4) * 8;
  const ushort_t* Ap = A + (size_t)(m0 + r) * K + ko;
  const ushort_t* Bp = BT + (size_t)b * strideBT + (size_t)(n0 + r) * K + ko;

  f32x4 acc[4][2];
  #pragma unroll
  for (int mi = 0; mi < 4; mi++)
    #pragma unroll
    for (int ni = 0; ni < 2; ni++) acc[mi][ni] = (f32x4){0.f, 0.f, 0.f, 0.f};

  for (int k0 = 0; k0 < K; k0 += 32) {
    bf16x8 fa[4], fb[2];
    #pragma unroll
    for (int mi = 0; mi < 4; mi++)
      fa[mi] = *(const bf16x8*)(Ap + (size_t)mi * 16 * K + k0);
    #pragma unroll
    for (int ni = 0; ni < 2; ni++)
      fb[ni] = *(const bf16x8*)(Bp + (size_t)ni * 16 * K + k0);
    #pragma unroll
    for (int mi = 0; mi < 4; mi++)
      #pragma unroll
      for (int ni = 0; ni < 2; ni++) {
        if constexpr (TOUT)
          acc[mi][ni] = __builtin_amdgcn_mfma_f32_16x16x32_bf16(fb[ni], fa[mi], acc[mi][ni], 0, 0, 0);
        else
          acc[mi][ni] = __builtin_amdgcn_mfma_f32_16x16x32_bf16(fa[mi], fb[ni], acc[mi][ni], 0, 0, 0);
      }
  }
  int cq = (lane >> 4) * 4;
  if constexpr (TOUT) {
    #pragma unroll
    for (int ni = 0; ni < 2; ni++)
      #pragma unroll
      for (int rg = 0; rg < 4; rg++) {
        long n = n0 + ni * 16 + cq + rg;
        OutT* cp = C + (size_t)b * strideC + n * ldc + m0 + (lane & 15);
        #pragma unroll
        for (int mi = 0; mi < 4; mi++) {
          float v = acc[mi][ni][rg];
          if constexpr (sizeof(OutT) == 2) cp[mi * 16] = f2bf(v);
          else                             cp[mi * 16] = v;
        }
      }
  } else {
    #pragma unroll
    for (int mi = 0; mi < 4; mi++)
      #pragma unroll
      for (int rg = 0; rg < 4; rg++) {
        int m = m0 + mi * 16 + cq + rg;
        float bv = bias ? bias[m] : 0.f;
        OutT* cp = C + (size_t)b * strideC + (size_t)m * ldc + n0 + (lane & 15);
        #pragma unroll
        for (int ni = 0; ni < 2; ni++)
          cp[ni * 16] = acc[mi][ni][rg] + bv;
      }
  }
}

// ---------------------------------------------------------------------------
// Conv: causal depthwise k=4 + bias + SiLU.  LDS-staged xzT u-half rows
// (coalesced), 32 t per block, all 384 d. Writes u_t[b][t][d] bf16.
__global__ __launch_bounds__(384) void conv_silu_kernel(
    const ushort_t* __restrict__ xzT, const float* __restrict__ conv_w,
    const float* __restrict__ conv_b, ushort_t* __restrict__ u_t) {
  __shared__ ushort_t Us[CVT + 3][DI];
  int t0 = blockIdx.x * CVT;
  int b = blockIdx.y;
  int tid = threadIdx.x;          // d
  #pragma unroll
  for (int r = 0; r < CVT + 3; r++) {
    int t = t0 - 3 + r;
    Us[r][tid] = (t >= 0) ? xzT[((size_t)b * LL + t) * XZS + tid] : (ushort_t)0;
  }
  float w0 = conv_w[tid * 4 + 0], w1 = conv_w[tid * 4 + 1];
  float w2 = conv_w[tid * 4 + 2], w3 = conv_w[tid * 4 + 3];
  float cb = conv_b[tid];
  __syncthreads();
  ushort_t* up = u_t + ((size_t)b * LL + t0) * DI + tid;
  float xm3 = bf2f(Us[0][tid]);
  float xm2 = bf2f(Us[1][tid]);
  float xm1 = bf2f(Us[2][tid]);
  #pragma unroll
  for (int t = 0; t < CVT; t++) {
    float xc = bf2f(Us[t + 3][tid]);
    float a = cb + w3 * xc + w2 * xm1 + w1 * xm2 + w0 * xm3;
    float sv = a / (1.f + __expf(-a));
    up[(size_t)t * DI] = f2bf(sv);
    xm3 = xm2; xm2 = xm1; xm1 = xc;
  }
}

// ---------------------------------------------------------------------------
// dt_t[b][t][d] fp32 = softplus(dt_proj_w @ dblT[t][0..11] + dt_proj_b)
// 32 t per block, LDS-staged dt_low, fast softplus.
__global__ __launch_bounds__(384) void dt_kernel(
    const float* __restrict__ dblT, const float* __restrict__ dtw,
    const float* __restrict__ dtb, float* __restrict__ dt_t) {
  __shared__ float Ls[DTT * 12];
  int t0 = blockIdx.x * DTT;
  int b = blockIdx.y;
  int tid = threadIdx.x;          // d
  if (tid < DTT * 12) {
    int t = tid / 12, rr = tid - t * 12;
    Ls[tid] = dblT[((size_t)b * LL + t0 + t) * DBS + rr];
  }
  float dw[12];
  #pragma unroll
  for (int rr = 0; rr < 12; rr += 4)
    *(float4*)(dw + rr) = *(const float4*)(dtw + tid * 12 + rr);
  float db = dtb[tid];
  __syncthreads();
  float* op = dt_t + ((size_t)b * LL + t0) * DI + tid;
  #pragma unroll
  for (int t = 0; t < DTT; t++) {
    float acc = db;
    #pragma unroll
    for (int rr = 0; rr < 12; rr++) acc = fmaf(Ls[t * 12 + rr], dw[rr], acc);
    float v = (acc > 15.f) ? acc : __logf(1.f + __expf(acc));
    op[(size_t)t * DI] = v;
  }
}

// ---------------------------------------------------------------------------
// Scan phase 1: block=(chunk,b), 384 thr = 1 per channel d, 16 states/thread.
// B staged in LDS (reads are wave-uniform broadcasts). Decay product kept as
// running W = prod(w); P_j = W^(j+1) at chunk end (no end-exps).
__global__ __launch_bounds__(384) void scan_phase1(
    const float* __restrict__ dt_t, const ushort_t* __restrict__ u_t,
    const float* __restrict__ dblT, const float* __restrict__ A_log,
    float* __restrict__ hend, float* __restrict__ Pbuf) {
  __shared__ __align__(16) float Bs[CLEN * NST];
  int tid = threadIdx.x;
  int chunk = blockIdx.x, b = blockIdx.y;
  int t0 = chunk * CLEN;
  for (int i = tid; i < CLEN * NST; i += 384) {
    int t = i >> 4, s = i & 15;
    Bs[i] = dblT[((size_t)b * LL + t0 + t) * DBS + RDT + s];
  }
  int d = tid;
  int bd = b * DI + d;
  float av0 = -expf(A_log[d * NST]);
  float av_[NST];
  bool ok = true;
  #pragma unroll
  for (int j = 0; j < NST; j++) {
    av_[j] = -expf(A_log[d * NST + j]);
    ok = ok && (fabsf(av_[j] - av0 * (float)(j + 1)) <= 1e-4f * fabsf(av_[j]));
  }
  __syncthreads();
  const float* dtp = dt_t + ((size_t)b * LL + t0) * DI + d;
  const ushort_t* up = u_t + ((size_t)b * LL + t0) * DI + d;
  float h[NST];
  #pragma unroll
  for (int j = 0; j < NST; j++) h[j] = 0.f;

  size_t o = ((size_t)bd * NC + chunk) * NST;
  if (__all(ok)) {
    float W = 1.f;
    #pragma unroll 2
    for (int t = 0; t < CLEN; t++) {
      float dtv = dtp[(size_t)t * DI];
      float uv  = bf2f(up[(size_t)t * DI]);
      float q = dtv * uv;
      float w = __expf(dtv * av0);
      W *= w;
      float dA = w;
      #pragma unroll
      for (int j = 0; j < NST; j += 4) {
        float4 B4 = *(const float4*)(&Bs[t * NST + j]);
        h[j + 0] = fmaf(dA, h[j + 0], q * B4.x); dA *= w;
        h[j + 1] = fmaf(dA, h[j + 1], q * B4.y); dA *= w;
        h[j + 2] = fmaf(dA, h[j + 2], q * B4.z); dA *= w;
        h[j + 3] = fmaf(dA, h[j + 3], q * B4.w); dA *= w;
      }
    }
    #pragma unroll
    for (int j = 0; j < NST; j += 4)
      *(float4*)(hend + o + j) = make_float4(h[j], h[j+1], h[j+2], h[j+3]);
    float P[NST];
    float pj = W;
    #pragma unroll
    for (int j = 0; j < NST; j++) { P[j] = pj; pj *= W; }
    #pragma unroll
    for (int j = 0; j < NST; j += 4)
      *(float4*)(Pbuf + o + j) = make_float4(P[j], P[j+1], P[j+2], P[j+3]);
  } else {
    float S = 0.f;
    for (int t = 0; t < CLEN; t++) {
      float dtv = dtp[(size_t)t * DI];
      float uv  = bf2f(up[(size_t)t * DI]);
      float q = dtv * uv;
      S += dtv;
      #pragma unroll
      for (int j = 0; j < NST; j++)
        h[j] = __expf(dtv * av_[j]) * h[j] + q * Bs[t * NST + j];
    }
    #pragma unroll
    for (int j = 0; j < NST; j++) {
      hend[o + j] = h[j];
      Pbuf[o + j] = __expf(S * av_[j]);
    }
  }
}

// ---------------------------------------------------------------------------
// Scan combine: block per bd (768 blocks), 256 thr = (g=tid>>4 chunk-group,
// s=tid&15 state). Serial compose 16 chunks/thread, LDS exclusive scan over
// groups, replay writing carry-in into hend.
__global__ __launch_bounds__(256) void scan_combine(
    float* __restrict__ hend, const float* __restrict__ Pbuf) {
  __shared__ float sP[16][16], sH[16][16];
  int bd = blockIdx.x;
  int s = threadIdx.x & 15, g = threadIdx.x >> 4;
  size_t base = ((size_t)bd * NC + g * 16) * NST + s;
  // pass 1: local compose
  float Pl = 1.f, Hl = 0.f;
  #pragma unroll
  for (int k = 0; k < 16; k++) {
    size_t o = base + (size_t)k * NST;
    float p = Pbuf[o], he = hend[o];
    Hl = fmaf(p, Hl, he);
    Pl *= p;
  }
  sP[g][s] = Pl; sH[g][s] = Hl;
  __syncthreads();
  // exclusive scan over g (16 threads serial, one per s)
  if (threadIdx.x < 16) {
    int ss = threadIdx.x;
    float c = 0.f;
    #pragma unroll
    for (int gg = 0; gg < 16; gg++) {
      float tmp = sH[gg][ss];
      float pp  = sP[gg][ss];
      sH[gg][ss] = c;
      c = fmaf(pp, c, tmp);
    }
  }
  __syncthreads();
  // pass 2: replay with carry, store exclusive prefix into hend
  float c = sH[g][s];
  #pragma unroll
  for (int k = 0; k < 16; k++) {
    size_t o = base + (size_t)k * NST;
    float p = Pbuf[o], he = hend[o];
    hend[o] = c;
    c = fmaf(p, c, he);
  }
}

// ---------------------------------------------------------------------------
// Scan phase 3: 1 thread per channel, 16 states; y in-register (no shuffle);
// ym_t[b][t][d] bf16 = (y + u*D) * silu(z).
__global__ __launch_bounds__(384) void scan_phase3(
    const float* __restrict__ dt_t, const ushort_t* __restrict__ u_t,
    const float* __restrict__ dblT, const float* __restrict__ A_log,
    const float* __restrict__ hin, const float* __restrict__ Dp,
    const ushort_t* __restrict__ xzT, ushort_t* __restrict__ ym_t) {
  __shared__ __align__(16) float Bs[CLEN * NST];
  __shared__ __align__(16) float Cs[CLEN * NST];
  int tid = threadIdx.x;
  int chunk = blockIdx.x, b = blockIdx.y;
  int t0 = chunk * CLEN;
  for (int i = tid; i < CLEN * 2 * NST; i += 384) {
    int t = i >> 5, s = i & 31;
    float v = dblT[((size_t)b * LL + t0 + t) * DBS + RDT + s];
    if (s < NST) Bs[t * NST + s] = v;
    else         Cs[t * NST + (s - NST)] = v;
  }
  int d = tid;
  int bd = b * DI + d;
  float av0 = -expf(A_log[d * NST]);
  float av_[NST];
  bool ok = true;
  #pragma unroll
  for (int j = 0; j < NST; j++) {
    av_[j] = -expf(A_log[d * NST + j]);
    ok = ok && (fabsf(av_[j] - av0 * (float)(j + 1)) <= 1e-4f * fabsf(av_[j]));
  }
  __syncthreads();
  const float* dtp = dt_t + ((size_t)b * LL + t0) * DI + d;
  const ushort_t* up = u_t + ((size_t)b * LL + t0) * DI + d;
  const ushort_t* zp = xzT + ((size_t)b * LL + t0) * XZS + DI + d;
  ushort_t* ymp = ym_t + ((size_t)b * LL + t0) * DI + d;

  float h[NST];
  const float* hi = hin + ((size_t)bd * NC + chunk) * NST;
  #pragma unroll
  for (int j = 0; j < NST; j += 4) {
    float4 v = *(const float4*)(hi + j);
    h[j] = v.x; h[j+1] = v.y; h[j+2] = v.z; h[j+3] = v.w;
  }
  float Dv = Dp[d];

  if (__all(ok)) {
    #pragma unroll 2
    for (int t = 0; t < CLEN; t++) {
      float dtv = dtp[(size_t)t * DI];
      float uv  = bf2f(up[(size_t)t * DI]);
      float zv  = bf2f(zp[(size_t)t * XZS]);
      float q = dtv * uv;
      float w = __expf(dtv * av0);
      float dA = w;
      float y0 = 0.f, y1 = 0.f, y2 = 0.f, y3 = 0.f;
      #pragma unroll
      for (int j = 0; j < NST; j += 4) {
        float4 B4 = *(const float4*)(&Bs[t * NST + j]);
        float4 C4 = *(const float4*)(&Cs[t * NST + j]);
        h[j + 0] = fmaf(dA, h[j + 0], q * B4.x); y0 = fmaf(h[j + 0], C4.x, y0); dA *= w;
        h[j + 1] = fmaf(dA, h[j + 1], q * B4.y); y1 = fmaf(h[j + 1], C4.y, y1); dA *= w;
        h[j + 2] = fmaf(dA, h[j + 2], q * B4.z); y2 = fmaf(h[j + 2], C4.z, y2); dA *= w;
        h[j + 3] = fmaf(dA, h[j + 3], q * B4.w); y3 = fmaf(h[j + 3], C4.w, y3); dA *= w;
      }
      float y = (y0 + y1) + (y2 + y3);
      float yv = (y + uv * Dv) * (zv / (1.f + __expf(-zv)));
      ymp[(size_t)t * DI] = f2bf(yv);
    }
  } else {
    for (int t = 0; t < CLEN; t++) {
      float dtv = dtp[(size_t)t * DI];
      float uv  = bf2f(up[(size_t)t * DI]);
      float zv  = bf2f(zp[(size_t)t * XZS]);
      float q = dtv * uv;
      float y = 0.f;
      #pragma unroll
      for (int j = 0; j < NST; j++) {
        h[j] = __expf(dtv * av_[j]) * h[j] + q * Bs[t * NST + j];
        y = fmaf(h[j], Cs[t * NST + j], y);
      }
      float yv = (y + uv * Dv) * (zv / (1.f + __expf(-zv)));
      ymp[(size_t)t * DI] = f2bf(yv);
    }
  }
}

// ---------------------------------------------------------------------------
extern "C" void kernel_launch(void* const* d_in, const int* in_sizes, int n_in,
                              void* d_out, int out_size, void* d_ws, size_t ws_size,
                              hipStream_t stream) {
  const float* x         = (const float*)d_in[0];
  const float* in_proj_w = (const float*)d_in[1];
  const float* conv_w    = (const float*)d_in[2];
  const float* conv_b    = (const float*)d_in[3];
  const float* x_proj_w  = (const float*)d_in[4];
  const float* dt_proj_w = (const float*)d_in[5];
  const float* dt_proj_b = (const float*)d_in[6];
  const float* A_log     = (const float*)d_in[7];
  const float* D_param   = (const float*)d_in[8];
  const float* out_proj_w= (const float*)d_in[9];
  const float* proj_w    = (const float*)d_in[10];
  const float* proj_b    = (const float*)d_in[11];
  float* out = (float*)d_out;

  // workspace layout (float units)
  float* w = (float*)d_ws;
  float*    mu     = w;                                   // 512
  float*    rstd   = w + 512;                             // 512
  float*    PW     = w + 1024;                            // 73,728
  ushort_t* PW_bf  = (ushort_t*)(w + 74752);              // 73,728 bf16 (36,864 f)
  ushort_t* ipw_bf = (ushort_t*)(w + 111616);             // 147,456 bf16 (73,728 f)
  ushort_t* xpw_bf = (ushort_t*)(w + 185344);             // 24,576 bf16 (12,288 f)
  ushort_t* xT     = (ushort_t*)(w + 197632);             // 6.29M bf16 (3,145,728 f)
  ushort_t* xzT    = (ushort_t*)(w + 3343360);            // 25.2M bf16 (12,582,912 f)
  ushort_t* u_t    = (ushort_t*)(w + 15926272);           // 12.6M bf16 (6,291,456 f)
  float*    dblT   = w + 22217728;                        // 2,097,152 f
  float*    dt_t   = w + 24314880;                        // 12,582,912 f
  ushort_t* ym_t   = (ushort_t*)(w + 36897792);           // 12.6M bf16 (6,291,456 f)
  float*    hend   = w + 43189248;                        // 3,145,728 f
  float*    Pbuf   = w + 46334976;                        // 3,145,728 f
  size_t need = 49480704;
  if (ws_size < need * sizeof(float)) return;

  norm_stats_kernel<<<dim3(BB * CM), dim3(256), 0, stream>>>(x, mu, rstd);
  fuse_proj_kernel<<<dim3((CM * DI + 255) / 256), dim3(256), 0, stream>>>(proj_w, out_proj_w, PW);
  cvt_weights_kernel<<<dim3((2 * DI * CM + 255) / 256), dim3(256), 0, stream>>>(
      in_proj_w, x_proj_w, PW, ipw_bf, xpw_bf, PW_bf);
  xt_norm_kernel<<<dim3(LL / 64, CM / 64, BB), dim3(256), 0, stream>>>(x, mu, rstd, xT);

  // GEMM1: xzT[b][t][768] = xT(BT) x in_proj_w   (M=768, K=192)
  gemm_mfma<true, ushort_t><<<dim3(12, 128, BB), dim3(256), 0, stream>>>(
      ipw_bf, xT, xzT, CM, (long)LL * CM, (long)LL * XZS, XZS, nullptr);

  conv_silu_kernel<<<dim3(LL / CVT, BB), dim3(384), 0, stream>>>(xzT, conv_w, conv_b, u_t);

  // GEMM2: dblT[b][t][64] = u_t(BT) x x_proj_w(padded)  (M=64, K=384)
  gemm_mfma<true, float><<<dim3(1, 128, BB), dim3(256), 0, stream>>>(
      xpw_bf, u_t, dblT, DI, (long)LL * DI, (long)LL * DBS, DBS, nullptr);

  dt_kernel<<<dim3(LL / DTT, BB), dim3(384), 0, stream>>>(dblT, dt_proj_w, dt_proj_b, dt_t);

  scan_phase1<<<dim3(NC, BB), dim3(384), 0, stream>>>(dt_t, u_t, dblT, A_log, hend, Pbuf);
  scan_combine<<<dim3(BB * DI), dim3(256), 0, stream>>>(hend, Pbuf);
  scan_phase3<<<dim3(NC, BB), dim3(384), 0, stream>>>(dt_t, u_t, dblT, A_log, hend, D_param, xzT, ym_t);

  // GEMM3: out[b][192][L] = PW x ym_t(BT) + proj_b  (M=192, K=384)
  gemm_mfma<false, float><<<dim3(3, 128, BB), dim3(256), 0, stream>>>(
      PW_bf, ym_t, out, DI, (long)LL * DI, (long)CM * LL, LL, proj_b);
}